// Round 5
// baseline (407.127 us; speedup 1.0000x reference)
//
#include <hip/hip_runtime.h>

// Complex MHA: T=1024, B=4, E=1024, H=16, HD=64.  SCALING = 0.125.
// Pipeline (all GEMMs real f16 C = A * B^T, fp32 accum, MFMA 16x16x32):
//  1. pack3:  AK0=xr, AK1=xi, AK2=xr+xi (4096x1024);  BW0=wr, BW1=wi, BW2=wr+wi (3072x1024)
//  2. proj (Karatsuba, one dispatch): T_z = AK_z BW_z^T  (4096x3072 each, K=1024)
//     256x192 tile, **4 waves (2x2 grid, per-wave 128x96)**, 2-phase pipelined
//     K-loop, asm ds_read + counted lgkmcnt, counted vmcnt(10).
//     History: r1/r2 4-phase/2-phase @8 waves = neutral (compiler vmcnt(0) fence
//     collapse); r4 asm-reads +12% (MfmaUtil 35). Remaining gap = LDS traffic:
//     8-wave 2x4 grid re-read A 4x -> 176+56 KiB/K-tile ~ 2400cy > MFMA 1862cy.
//     4 fat waves cut re-reads: 112+56 KiB -> MFMA-bound. 1 blk/CU anyway (112KiB
//     LDS), so 1 wave/SIMD costs nothing; VGPR budget 512 via launch_bounds(256,1).
//  3. pack_qk: P_re=T1-T2, P_im=T3-T1-T2 combined on the fly; per bh:
//              A_q=[qr|qi]*0.125 (1024x128), B_k=[kr+ki|kr-ki] (1024x128),
//              B_v=[vr^T;vi^T] (128x1024, transposed through LDS)
//  4. qk:    awr[bh] = A_q B_k^T (1024x1024) f16 + per-block min/max partials
//  5. minmax reduce -> mn, sc=1/(mx-mn);  colsum[bh][n] = sum_k B_v[bh][n][k]
//     pack Bo_re=[owr|-owi], Bo_im=[owi|owr] (1024x2048) into dead BK region
//  6. attn:  acc = awr B_v^T ; val = sc*acc - sc*mn*colsum -> A_attn (4096x2048)
//  7. out (one z=2 dispatch): d_out = A_attn Bo_{re,im}^T + ob  (K=2048, f32 out)
//  8. aw_avg: mean over h of awr, affine-corrected -> d_out[8M:12M)
//
// Old GEMM core kept for qk (K=128: pipeline can't fill), attn (N=128) and out2.

using half4 = __attribute__((__ext_vector_type__(4))) _Float16;
using half8 = __attribute__((__ext_vector_type__(8))) _Float16;
using f32x4 = __attribute__((__ext_vector_type__(4))) float;

// ---------------- workspace layout (bytes), total ~176.1 MiB ----------------
static constexpr size_t OFF_AWR    = 0;                         // 64*1024*1024*2 = 134217728
static constexpr size_t OFF_AQ     = 134217728;                 // 64*1024*128*2  = 16777216
static constexpr size_t OFF_BK     = 150994944;                 // 16777216
static constexpr size_t OFF_BV     = 167772160;                 // 16777216
static constexpr size_t OFF_COLSUM = 184549376;                 // 8192*4
static constexpr size_t OFF_PMIN   = 184582144;                 // 4096*4
static constexpr size_t OFF_PMAX   = 184598528;                 // 4096*4
static constexpr size_t OFF_SCAL   = 184614912;                 // 2 floats
// lifetime overlays:
static constexpr size_t OFF_AATTN  = OFF_AQ;                    // after AQ dead (16Mi)
static constexpr size_t OFF_BORE   = OFF_BK;                    // after BK dead (4Mi)
static constexpr size_t OFF_BOIM   = OFF_BK + 4194304;          // (4Mi)
// phase-1 buffers overlay the (later-written) awr region [0, 119.5MB):
static constexpr size_t OFF_AK0    = 0;                         // 3 x 4096*1024*2
static constexpr size_t AK_STRIDE  = 8388608;
static constexpr size_t OFF_BW0    = 25165824;                  // 3 x 3072*1024*2
static constexpr size_t BW_STRIDE  = 6291456;
static constexpr size_t OFF_PT0    = 44040192;                  // 3 x 4096*3072*2
static constexpr size_t PT_STRIDE  = 25165824;                  // ends 119537664 < 134217728

static __device__ __forceinline__ void gload_lds16(const void* g, void* l) {
    __builtin_amdgcn_global_load_lds(
        (__attribute__((address_space(1))) void*)(g),
        (__attribute__((address_space(3))) void*)(l), 16, 0, 0);
}

// raw LDS read, invisible to the compiler's waitcnt pass (no "memory" clobber):
// caller is responsible for s_waitcnt lgkmcnt(N) + sched_barrier(0) before use.
typedef __attribute__((address_space(3))) const _Float16 lds_cf16;
static __device__ __forceinline__ half8 ldsr_off(const _Float16* p, int imm) {
    half8 r;
    asm volatile("ds_read_b128 %0, %1 offset:%2"
                 : "=v"(r) : "v"((lds_cf16*)p), "i"(imm));
    return r;
}

// ---------------- legacy GEMM core: 128x128 tile, BK=64, 4 waves ----------------
// (unchanged; used by qk / attn / out2)
__device__ __forceinline__ void gemm_core(const _Float16* __restrict__ A,
                                          const _Float16* __restrict__ B,
                                          int K, int lda, int ldb,
                                          f32x4 acc[4][4]) {
    __shared__ _Float16 As[128 * 64];
    __shared__ _Float16 Bs[128 * 64];
    const int tid  = threadIdx.x;
    const int lane = tid & 63;
    const int w    = tid >> 6;
    const int wr   = w >> 1, wc = w & 1;
    const int quad = lane >> 4, l16 = lane & 15;
    const int grow = lane >> 3;                      // 0..7 row within 8-row group
    const int gcol = ((lane & 7) ^ grow) * 8;        // xor-swizzled 8-half chunk
    const _Float16* apw = A + (size_t)(w * 32 + grow) * lda + gcol;
    const _Float16* bpw = B + (size_t)(w * 32 + grow) * ldb + gcol;
    _Float16* lAw = &As[(w * 32) * 64];
    _Float16* lBw = &Bs[(w * 32) * 64];

    #pragma unroll
    for (int i = 0; i < 4; i++)
        #pragma unroll
        for (int j = 0; j < 4; j++) acc[i][j] = (f32x4){0.f, 0.f, 0.f, 0.f};

    const int rsw = l16 & 7;                         // frag row & 7 (un-swizzle)
    const int s0  = (quad ^ rsw) * 8;                // k-window [0,32)
    const int s1  = ((quad | 4) ^ rsw) * 8;          // k-window [32,64)
    for (int kt = 0; kt < K; kt += 64) {
        #pragma unroll
        for (int i = 0; i < 4; i++) {
            gload_lds16(apw + (size_t)(i * 8) * lda + kt, lAw + i * 512);
            gload_lds16(bpw + (size_t)(i * 8) * ldb + kt, lBw + i * 512);
        }
        __syncthreads();
        half8 af0[4], af1[4], bf0[4], bf1[4];
        #pragma unroll
        for (int i = 0; i < 4; i++) {
            const int row = (wr * 64 + i * 16 + l16) * 64;
            af0[i] = *(const half8*)(&As[row + s0]);
            af1[i] = *(const half8*)(&As[row + s1]);
        }
        #pragma unroll
        for (int j = 0; j < 4; j++) {
            const int row = (wc * 64 + j * 16 + l16) * 64;
            bf0[j] = *(const half8*)(&Bs[row + s0]);
            bf1[j] = *(const half8*)(&Bs[row + s1]);
        }
        #pragma unroll
        for (int i = 0; i < 4; i++)
            #pragma unroll
            for (int j = 0; j < 4; j++) {
                acc[i][j] = __builtin_amdgcn_mfma_f32_16x16x32_f16(af0[i], bf0[j], acc[i][j], 0, 0, 0);
                acc[i][j] = __builtin_amdgcn_mfma_f32_16x16x32_f16(af1[i], bf1[j], acc[i][j], 0, 0, 0);
            }
        __syncthreads();
    }
}

// C/D layout: row = quad*4 + reg, col = l16 (verified m89/m91).
#define EPILOGUE_COORDS()                               \
    const int lane = threadIdx.x & 63;                  \
    const int w    = threadIdx.x >> 6;                  \
    const int wr   = w >> 1, wc = w & 1;                \
    const int quad = lane >> 4, l16 = lane & 15;

// ---------------- kernels ----------------

// pack three Karatsuba operands: d0=s1, d1=s2, d2=s1+s2 (flat, 4 elems/thread)
__global__ __launch_bounds__(256) void k_pack3(_Float16* __restrict__ d0,
                                               _Float16* __restrict__ d1,
                                               _Float16* __restrict__ d2,
                                               const float* __restrict__ s1,
                                               const float* __restrict__ s2, int n4) {
    int i4 = blockIdx.x * 256 + threadIdx.x;
    if (i4 >= n4) return;
    size_t idx = (size_t)i4 << 2;
    f32x4 a = *(const f32x4*)(s1 + idx);
    f32x4 b = *(const f32x4*)(s2 + idx);
    half4 h0, h1, h2;
    #pragma unroll
    for (int e = 0; e < 4; e++) {
        h0[e] = (_Float16)a[e]; h1[e] = (_Float16)b[e]; h2[e] = (_Float16)(a[e] + b[e]);
    }
    *(half4*)(d0 + idx) = h0;
    *(half4*)(d1 + idx) = h1;
    *(half4*)(d2 + idx) = h2;
}

// vectorized pack: 4 elements/thread; dst row = [s1 | sgn2*s2]
__global__ __launch_bounds__(256) void k_pack2(_Float16* __restrict__ dst,
                                               const float* __restrict__ s1,
                                               const float* __restrict__ s2,
                                               float sgn2, int n4) {
    int i4 = blockIdx.x * 256 + threadIdx.x;
    if (i4 >= n4) return;
    int r = i4 >> 8, c4 = (i4 & 255) << 2;
    size_t src = ((size_t)r << 10) + c4;
    f32x4 a = *(const f32x4*)(s1 + src);
    f32x4 b = *(const f32x4*)(s2 + src);
    half4 ha, hb;
    #pragma unroll
    for (int e = 0; e < 4; e++) { ha[e] = (_Float16)a[e]; hb[e] = (_Float16)(sgn2 * b[e]); }
    size_t o = ((size_t)r << 11) + c4;
    *(half4*)(dst + o)        = ha;
    *(half4*)(dst + o + 1024) = hb;
}

// ================== pipelined Karatsuba proj GEMM (4 fat waves) ==================
// Tile 256(M) x 192(N), BK=64, 256 threads = 4 waves, wave grid 2(M) x 2(N),
// per-wave output 128x96 -> acc[8][6] f32x4 (192 regs, AGPR side).
// LDS: double-buffered As[2][256][64] (64 KiB) + Bs[2][192][64] (48 KiB) = 112 KiB,
// row r slot s (8 halfs) holds global chunk s^(r&7)  (verified swizzle, 0 conflicts).
// LDS read traffic per K-tile: 4 waves x (A 16KiB + B 12KiB) = 112 KiB (A re-read
// 2x, B 2x) vs 176 KiB at 8 waves -> MFMA (1862cy) becomes the max term.
// Staging: 32-row units (1 gload_lds16/thread/unit): A0..A7, B0..B5 (14/thread).
// Per K-tile t (buf bb = t&1, nb = bb^1), 2 barriers:
//   [issue 28 asm ds_reads: fB(12), fA m0..3(8), then fA m4..7(8)]
//   [stage t+1-late: A2,A3,A6,A7 -> nb]
//   lgkmcnt(8)  (first 20 = fB+fA03 done; fA47 in flight, serviced under MFMA0)
//   sched_barrier; setprio1; 48 MFMA (m0..3 x n0..5); setprio0
//   s_barrier   (all waves' reads of bb{B all, A0,A1,A4,A5} complete)
//   [stage t+2-early: B0..B5, A0,A1,A4,A5 -> bb]
//   lgkmcnt(0); sched_barrier; setprio1; 48 MFMA (m4..7); setprio0
//   vmcnt(10) steady / vmcnt(0) at t=NT-2; sched_barrier; s_barrier
// Hazard ledger (re-derived for 2x2 grid):
//  - ph0 reads cover exactly bb{B units 0-5 (wc0:0-2, wc1:3-5), A units 0,1 (wr0)
//    /4,5 (wr1)}; awaited by lgkmcnt(8) before MFMA0, before the mid barrier;
//    ph1's t+2 stages into those bb regions issue after it. SAFE.
//  - hoisted fA47 reads (bb A units 2,3 / 6,7) vs ph1 stages: disjoint. SAFE.
//  - ph0 stages (nb A2,3,6,7 of t+1): those nb regions were last read at t-1 ph1,
//    awaited by its lgkmcnt(0) before t-1's end barrier. SAFE.
//  - vmcnt(10) at end of t: in-order outstanding = [t-1.ph1: 10 = t+1-early]
//    [t.ph0: 4 = t+1-late] [t.ph1: 10 = t+2-early]; waiting to 10 completes the
//    first 14 = ALL of tile t+1. Prologue mirrors: 14 (t0) + 10 (t1-early),
//    vmcnt(10) -> t0 landed. Epilogue t=NT-2: vmcnt(0) drains t+1 fully.
__global__ __launch_bounds__(256, 1) void k_gemm_proj(const _Float16* __restrict__ AK,
                                                      const _Float16* __restrict__ BW,
                                                      _Float16* __restrict__ PT) {
    __shared__ _Float16 As[2][256 * 64];   // 64 KiB
    __shared__ _Float16 Bs[2][192 * 64];   // 48 KiB

    // grid: 768 = 16(M) x 16(N) x 3(z); bijective XCD swizzle (768 = 8*96).
    const int bid = blockIdx.x;
    const int wg  = (bid & 7) * 96 + (bid >> 3);
    const int z   = wg >> 8;                 // 0..2
    const int rem = wg & 255;
    const int my  = rem >> 4, nx = rem & 15; // nx fast -> A panel stays hot in XCD L2

    const _Float16* A = AK + (size_t)z * (AK_STRIDE / 2) + ((size_t)my << 18);
    const _Float16* B = BW + (size_t)z * (BW_STRIDE / 2) + (size_t)nx * 196608;
    _Float16*       C = PT + (size_t)z * (PT_STRIDE / 2);

    const int tid  = threadIdx.x;
    const int lane = tid & 63;
    const int w    = tid >> 6;               // 0..3
    const int wr   = w >> 1, wc = w & 1;     // 2 x 2 wave grid
    const int quad = lane >> 4, l16 = lane & 15;
    const int rowoff = tid >> 3;             // 0..31 : row within a 32-row unit
    const int chunk8 = ((tid & 7) ^ (rowoff & 7)) << 3;  // pre-swizzled global chunk
    const int rsw = l16 & 7;
    const int s0  = (quad ^ rsw) << 3;       // k-window [0,32)
    const int s1  = ((quad | 4) ^ rsw) << 3; // k-window [32,64)
    const int abase = ((wr << 7) + l16) << 6;      // (wr*128 + l16) * 64
    const int bbase = (wc * 96 + l16) << 6;        // (wc*96  + l16) * 64

    const _Float16* Ast = A + ((size_t)rowoff << 10) + chunk8;  // per-lane global src
    const _Float16* Bst = B + ((size_t)rowoff << 10) + chunk8;
    _Float16* Alds = (_Float16*)As;
    _Float16* Blds = (_Float16*)Bs;

    // LDS dst is wave-uniform (HW adds lane*16B): unit u -> u*2048 halfs, wave w
    // covers rows 8w..8w+7 of the unit -> +w*512 halfs.
    auto stA = [&](int buf, int u, int kt) {
        gload_lds16(Ast + ((size_t)u << 15) + kt,
                    Alds + buf * 16384 + (u << 11) + (w << 9));
    };
    auto stB = [&](int buf, int u, int kt) {
        gload_lds16(Bst + ((size_t)u << 15) + kt,
                    Blds + buf * 12288 + (u << 11) + (w << 9));
    };

    f32x4 acc[8][6];
    #pragma unroll
    for (int i = 0; i < 8; i++)
        #pragma unroll
        for (int j = 0; j < 6; j++) acc[i][j] = (f32x4){0.f, 0.f, 0.f, 0.f};

    // prologue: tile0 all 14 units, then tile1-early {B0..5, A0,A1,A4,A5}
    stB(0, 0, 0); stB(0, 1, 0); stB(0, 2, 0); stB(0, 3, 0); stB(0, 4, 0); stB(0, 5, 0);
    stA(0, 0, 0); stA(0, 1, 0); stA(0, 2, 0); stA(0, 3, 0);
    stA(0, 4, 0); stA(0, 5, 0); stA(0, 6, 0); stA(0, 7, 0);
    stB(1, 0, 64); stB(1, 1, 64); stB(1, 2, 64); stB(1, 3, 64); stB(1, 4, 64); stB(1, 5, 64);
    stA(1, 0, 64); stA(1, 1, 64); stA(1, 4, 64); stA(1, 5, 64);
    asm volatile("s_waitcnt vmcnt(10)" ::: "memory");  // tile0's 14 units landed
    __builtin_amdgcn_sched_barrier(0);
    __builtin_amdgcn_s_barrier();

    constexpr int NT = 16;   // K = 1024
    #pragma unroll 1
    for (int t = 0; t < NT; ++t) {
        const int bb = t & 1, nb = bb ^ 1;
        const int kt = t << 6;
        const _Float16* pAb = Alds + bb * 16384;
        const _Float16* pBb = Blds + bb * 12288;
        const bool p1 = (t + 1 < NT), p2 = (t + 2 < NT);
        // four address registers; all 28 reads use compile-time offset: immediates
        const _Float16* aA0 = pAb + abase + s0;
        const _Float16* aA1 = pAb + abase + s1;
        const _Float16* aB0 = pBb + bbase + s0;
        const _Float16* aB1 = pBb + bbase + s1;
        half8 fB[6][2], fA[8][2];
        // ---- issue fB(12) + fA m0..3 (8) first (awaited by lgkmcnt(8)) ----
        fB[0][0] = ldsr_off(aB0, 0);     fB[0][1] = ldsr_off(aB1, 0);
        fB[1][0] = ldsr_off(aB0, 2048);  fB[1][1] = ldsr_off(aB1, 2048);
        fB[2][0] = ldsr_off(aB0, 4096);  fB[2][1] = ldsr_off(aB1, 4096);
        fB[3][0] = ldsr_off(aB0, 6144);  fB[3][1] = ldsr_off(aB1, 6144);
        fB[4][0] = ldsr_off(aB0, 8192);  fB[4][1] = ldsr_off(aB1, 8192);
        fB[5][0] = ldsr_off(aB0, 10240); fB[5][1] = ldsr_off(aB1, 10240);
        fA[0][0] = ldsr_off(aA0, 0);     fA[0][1] = ldsr_off(aA1, 0);
        fA[1][0] = ldsr_off(aA0, 2048);  fA[1][1] = ldsr_off(aA1, 2048);
        fA[2][0] = ldsr_off(aA0, 4096);  fA[2][1] = ldsr_off(aA1, 4096);
        fA[3][0] = ldsr_off(aA0, 6144);  fA[3][1] = ldsr_off(aA1, 6144);
        // ---- then fA m4..7 (8): left in flight across MFMA0 ----
        fA[4][0] = ldsr_off(aA0, 8192);  fA[4][1] = ldsr_off(aA1, 8192);
        fA[5][0] = ldsr_off(aA0, 10240); fA[5][1] = ldsr_off(aA1, 10240);
        fA[6][0] = ldsr_off(aA0, 12288); fA[6][1] = ldsr_off(aA1, 12288);
        fA[7][0] = ldsr_off(aA0, 14336); fA[7][1] = ldsr_off(aA1, 14336);
        if (p1) { stA(nb, 2, kt + 64); stA(nb, 3, kt + 64);
                  stA(nb, 6, kt + 64); stA(nb, 7, kt + 64); }
        asm volatile("s_waitcnt lgkmcnt(8)" ::: "memory");
        __builtin_amdgcn_sched_barrier(0);
        __builtin_amdgcn_s_setprio(1);
        #pragma unroll
        for (int i = 0; i < 4; i++)
            #pragma unroll
            for (int n = 0; n < 6; n++) {
                acc[i][n] = __builtin_amdgcn_mfma_f32_16x16x32_f16(fA[i][0], fB[n][0], acc[i][n], 0, 0, 0);
                acc[i][n] = __builtin_amdgcn_mfma_f32_16x16x32_f16(fA[i][1], fB[n][1], acc[i][n], 0, 0, 0);
            }
        __builtin_amdgcn_s_setprio(0);
        __builtin_amdgcn_s_barrier();
        // ---- stage t+2-early into bb (regions fully consumed above), MFMA m4..7
        if (p2) {
            stB(bb, 0, kt + 128); stB(bb, 1, kt + 128); stB(bb, 2, kt + 128);
            stB(bb, 3, kt + 128); stB(bb, 4, kt + 128); stB(bb, 5, kt + 128);
            stA(bb, 0, kt + 128); stA(bb, 1, kt + 128);
            stA(bb, 4, kt + 128); stA(bb, 5, kt + 128);
        }
        asm volatile("s_waitcnt lgkmcnt(0)" ::: "memory");
        __builtin_amdgcn_sched_barrier(0);
        __builtin_amdgcn_s_setprio(1);
        #pragma unroll
        for (int i = 0; i < 4; i++)
            #pragma unroll
            for (int n = 0; n < 6; n++) {
                acc[i + 4][n] = __builtin_amdgcn_mfma_f32_16x16x32_f16(fA[i + 4][0], fB[n][0], acc[i + 4][n], 0, 0, 0);
                acc[i + 4][n] = __builtin_amdgcn_mfma_f32_16x16x32_f16(fA[i + 4][1], fB[n][1], acc[i + 4][n], 0, 0, 0);
            }
        __builtin_amdgcn_s_setprio(0);
        if (p2)      { asm volatile("s_waitcnt vmcnt(10)" ::: "memory"); }
        else if (p1) { asm volatile("s_waitcnt vmcnt(0)" ::: "memory"); }
        __builtin_amdgcn_sched_barrier(0);
        __builtin_amdgcn_s_barrier();
    }

    // epilogue: C f16, ld 3072
    const int m0 = my << 8, n0 = nx * 192;
    #pragma unroll
    for (int m = 0; m < 8; m++)
        #pragma unroll
        for (int n = 0; n < 6; n++)
            #pragma unroll
            for (int r = 0; r < 4; r++) {
                int row = m0 + wr * 128 + m * 16 + quad * 4 + r;
                int col = n0 + wc * 96 + n * 16 + l16;
                C[(size_t)row * 3072 + col] = (_Float16)acc[m][n][r];
            }
}

// per (bh, 64-t slab): combine T1,T2,T3 -> q,k,v; build Aq, Bk (coalesced) and
// Bv (transposed via LDS)
__global__ __launch_bounds__(256) void k_pack_qk(const _Float16* __restrict__ T1,
                                                 const _Float16* __restrict__ T2,
                                                 const _Float16* __restrict__ T3,
                                                 const float* __restrict__ b_re,
                                                 const float* __restrict__ b_im,
                                                 _Float16* __restrict__ Aq,
                                                 _Float16* __restrict__ Bk,
                                                 _Float16* __restrict__ Bv) {
    __shared__ _Float16 vt[128 * 66];            // [hd2][tloc], pad 64->66
    const int bh = blockIdx.y, t0 = blockIdx.x * 64;
    const int b = bh >> 4, h = bh & 15;
    const int tid = threadIdx.x;
    const int hd = tid & 63, tg = tid >> 6;      // 4 t-rows per pass
    const int e = h * 64 + hd;
    for (int pass = 0; pass < 16; pass++) {
        int tloc = pass * 4 + tg;
        int t = t0 + tloc;
        size_t mrow = (size_t)(t * 4 + b) * 3072;
        float q1 = (float)T1[mrow + e], q2 = (float)T2[mrow + e], q3 = (float)T3[mrow + e];
        float k1 = (float)T1[mrow + 1024 + e], k2 = (float)T2[mrow + 1024 + e], k3 = (float)T3[mrow + 1024 + e];
        float v1 = (float)T1[mrow + 2048 + e], v2 = (float)T2[mrow + 2048 + e], v3 = (float)T3[mrow + 2048 + e];
        float qr = q1 - q2 + b_re[e];
        float qi = q3 - q1 - q2 + b_im[e];
        float kr = k1 - k2 + b_re[1024 + e];
        float ki = k3 - k1 - k2 + b_im[1024 + e];
        float vr = v1 - v2 + b_re[2048 + e];
        float vi = v3 - v1 - v2 + b_im[2048 + e];
        size_t qbase = ((size_t)bh * 1024 + t) * 128;
        Aq[qbase + hd]      = (_Float16)(qr * 0.125f);
        Aq[qbase + 64 + hd] = (_Float16)(qi * 0.125f);
        Bk[qbase + hd]      = (_Float16)(kr + ki);
        Bk[qbase + 64 + hd] = (_Float16)(kr - ki);
        vt[hd * 66 + tloc]        = (_Float16)vr;
        vt[(64 + hd) * 66 + tloc] = (_Float16)vi;
    }
    __syncthreads();
    // write Bv rows: 4 threads cover one row's 64 cols (2 x half8 each)
    size_t vbase = (size_t)bh * 131072;          // 128*1024
    const int j = tid & 3;
    #pragma unroll
    for (int half_ = 0; half_ < 2; half_++) {
        int r = (tid >> 2) + half_ * 64;
        _Float16* dst = Bv + vbase + (size_t)r * 1024 + t0 + j * 16;
        const _Float16* src = &vt[r * 66 + j * 16];
        *(half8*)dst       = *(const half8*)src;
        *(half8*)(dst + 8) = *(const half8*)(src + 8);
    }
}

__global__ __launch_bounds__(256) void k_gemm_qk(const _Float16* __restrict__ Aq,
                                                 const _Float16* __restrict__ Bk,
                                                 _Float16* __restrict__ awr,
                                                 float* __restrict__ pmin,
                                                 float* __restrict__ pmax) {
    const int bh = blockIdx.z;
    const int m0 = blockIdx.y * 128, n0 = blockIdx.x * 128;
    f32x4 acc[4][4];
    gemm_core(Aq + (size_t)bh * 131072 + (size_t)m0 * 128,
              Bk + (size_t)bh * 131072 + (size_t)n0 * 128, 128, 128, 128, acc);
    EPILOGUE_COORDS();
    _Float16* C = awr + ((size_t)bh << 20);
    float tmn = 3.0e38f, tmx = -3.0e38f;
    #pragma unroll
    for (int i = 0; i < 4; i++)
        #pragma unroll
        for (int j = 0; j < 4; j++)
            #pragma unroll
            for (int r = 0; r < 4; r++) {
                float v = acc[i][j][r];
                tmn = fminf(tmn, v); tmx = fmaxf(tmx, v);
                int m = m0 + wr * 64 + i * 16 + quad * 4 + r;
                int n = n0 + wc * 64 + j * 16 + l16;
                C[((size_t)m << 10) + n] = (_Float16)v;
            }
    __shared__ float smn[256], smx[256];
    int tid = threadIdx.x;
    smn[tid] = tmn; smx[tid] = tmx;
    __syncthreads();
    for (int s = 128; s > 0; s >>= 1) {
        if (tid < s) { smn[tid] = fminf(smn[tid], smn[tid + s]); smx[tid] = fmaxf(smx[tid], smx[tid + s]); }
        __syncthreads();
    }
    if (tid == 0) {
        int bid = (blockIdx.z * gridDim.y + blockIdx.y) * gridDim.x + blockIdx.x;
        pmin[bid] = smn[0]; pmax[bid] = smx[0];
    }
}

__global__ __launch_bounds__(256) void k_minmax(const float* __restrict__ pmin,
                                                const float* __restrict__ pmax,
                                                int n, float* __restrict__ scal) {
    __shared__ float smn[256], smx[256];
    int tid = threadIdx.x;
    float mn = 3.0e38f, mx = -3.0e38f;
    for (int i = tid; i < n; i += 256) { mn = fminf(mn, pmin[i]); mx = fmaxf(mx, pmax[i]); }
    smn[tid] = mn; smx[tid] = mx;
    __syncthreads();
    for (int s = 128; s > 0; s >>= 1) {
        if (tid < s) { smn[tid] = fminf(smn[tid], smn[tid + s]); smx[tid] = fmaxf(smx[tid], smx[tid + s]); }
        __syncthreads();
    }
    if (tid == 0) { scal[0] = smn[0]; scal[1] = 1.0f / (smx[0] - smn[0]); }
}

__global__ __launch_bounds__(256) void k_colsum(const _Float16* __restrict__ Bv,
                                                float* __restrict__ colsum) {
    int row  = blockIdx.x * 4 + (threadIdx.x >> 6);   // 0..8191 = bh*128+n
    int lane = threadIdx.x & 63;
    const _Float16* p = Bv + (size_t)row * 1024;
    float s = 0.f;
    for (int i = lane; i < 1024; i += 64) s += (float)p[i];
    #pragma unroll
    for (int off = 32; off > 0; off >>= 1) s += __shfl_down(s, off, 64);
    if (lane == 0) colsum[row] = s;
}

__global__ __launch_bounds__(256) void k_gemm_attn(const _Float16* __restrict__ awr,
                                                   const _Float16* __restrict__ Bv,
                                                   _Float16* __restrict__ Aattn,
                                                   const float* __restrict__ scal,
                                                   const float* __restrict__ colsum) {
    const int bh = blockIdx.z;
    const int m0 = blockIdx.y * 128;                 // N=128 -> single block col
    f32x4 acc[4][4];
    gemm_core(awr + ((size_t)bh << 20) + (size_t)m0 * 1024,
              Bv + (size_t)bh * 131072, 1024, 1024, 1024, acc);
    EPILOGUE_COORDS();
    const float sc = scal[1];
    const float c0 = sc * scal[0];                   // sc*mn
    const int b = bh >> 4, h = bh & 15;
    #pragma unroll
    for (int i = 0; i < 4; i++)
        #pragma unroll
        for (int j = 0; j < 4; j++)
            #pragma unroll
            for (int r = 0; r < 4; r++) {
                int m = m0 + wr * 64 + i * 16 + quad * 4 + r;   // q position
                int n = wc * 64 + j * 16 + l16;                 // 0..127
                float v = sc * acc[i][j][r] - c0 * colsum[bh * 128 + n];
                int e = (n < 64) ? (h * 64 + n) : (1024 + h * 64 + n - 64);
                Aattn[(size_t)(m * 4 + b) * 2048 + e] = (_Float16)v;
            }
}

// merged out-projection: z=0 -> re (Bre, ob_re), z=1 -> im (Bim, ob_im)
__global__ __launch_bounds__(256) void k_gemm_out2(const _Float16* __restrict__ A,
                                                   const _Float16* __restrict__ Bre,
                                                   const _Float16* __restrict__ Bim,
                                                   float* __restrict__ outp,
                                                   const float* __restrict__ ob_re,
                                                   const float* __restrict__ ob_im) {
    const int z = blockIdx.z;
    const _Float16* B = z ? Bim : Bre;
    const float* bias = z ? ob_im : ob_re;
    float* out = outp + (size_t)z * 4194304;
    const int m0 = blockIdx.y * 128, n0 = blockIdx.x * 128;
    f32x4 acc[4][4];
    gemm_core(A + (size_t)m0 * 2048, B + (size_t)n0 * 2048, 2048, 2048, 2048, acc);
    EPILOGUE_COORDS();
    #pragma unroll
    for (int i = 0; i < 4; i++)
        #pragma unroll
        for (int j = 0; j < 4; j++)
            #pragma unroll
            for (int r = 0; r < 4; r++) {
                int m = m0 + wr * 64 + i * 16 + quad * 4 + r;
                int n = n0 + wc * 64 + j * 16 + l16;
                out[((size_t)m << 10) + n] = acc[i][j][r] + bias[n];
            }
}

__global__ __launch_bounds__(256) void k_awavg(const _Float16* __restrict__ awr,
                                               const float* __restrict__ scal,
                                               float* __restrict__ out) {
    int i = blockIdx.x * 256 + threadIdx.x;          // over b(4) x q(1024) x k8(128)
    int k = (i & 127) * 8, q = (i >> 7) & 1023, b = i >> 17;
    float s[8] = {0, 0, 0, 0, 0, 0, 0, 0};
    size_t base = ((size_t)b << 24) + ((size_t)q << 10) + k;
    #pragma unroll
    for (int h = 0; h < 16; h++) {
        half8 v = *(const half8*)(awr + base + ((size_t)h << 20));
        #pragma unroll
        for (int e = 0; e < 8; e++) s[e] += (float)v[e];
    }
    const float mn = scal[0], sc = scal[1];
    float* dst = out + ((size_t)b << 20) + ((size_t)q << 10) + k;
    f32x4 o0, o1;
    #pragma unroll
    for (int e = 0; e < 4; e++) o0[e] = (s[e] * 0.0625f - mn) * sc;
    #pragma unroll
    for (int e = 0; e < 4; e++) o1[e] = (s[4 + e] * 0.0625f - mn) * sc;
    *(f32x4*)dst = o0;
    *(f32x4*)(dst + 4) = o1;
}

extern "C" void kernel_launch(void* const* d_in, const int* in_sizes, int n_in,
                              void* d_out, int out_size, void* d_ws, size_t ws_size,
                              hipStream_t stream) {
    const float* x_re  = (const float*)d_in[0];
    const float* x_im  = (const float*)d_in[1];
    const float* w_re  = (const float*)d_in[2];
    const float* w_im  = (const float*)d_in[3];
    const float* b_re  = (const float*)d_in[4];
    const float* b_im  = (const float*)d_in[5];
    const float* ow_re = (const float*)d_in[6];
    const float* ow_im = (const float*)d_in[7];
    const float* ob_re = (const float*)d_in[8];
    const float* ob_im = (const float*)d_in[9];

    char* ws = (char*)d_ws;
    _Float16* AWR   = (_Float16*)(ws + OFF_AWR);
    _Float16* AQ    = (_Float16*)(ws + OFF_AQ);
    _Float16* BK    = (_Float16*)(ws + OFF_BK);
    _Float16* BV    = (_Float16*)(ws + OFF_BV);
    _Float16* AATTN = (_Float16*)(ws + OFF_AATTN);
    _Float16* BORE  = (_Float16*)(ws + OFF_BORE);
    _Float16* BOIM  = (_Float16*)(ws + OFF_BOIM);
    float*    CSUM  = (float*)(ws + OFF_COLSUM);
    float*    PMIN  = (float*)(ws + OFF_PMIN);
    float*    PMAX  = (float*)(ws + OFF_PMAX);
    float*    SCAL  = (float*)(ws + OFF_SCAL);
    _Float16* AK    = (_Float16*)(ws + OFF_AK0);
    _Float16* BW    = (_Float16*)(ws + OFF_BW0);
    _Float16* PT    = (_Float16*)(ws + OFF_PT0);

    // 1. Karatsuba operand packing: AK0=xr, AK1=xi, AK2=xr+xi; BW likewise for w
    k_pack3<<<4096, 256, 0, stream>>>(AK, AK + AK_STRIDE / 2, AK + AK_STRIDE,
                                      x_re, x_im, 1048576);
    k_pack3<<<3072, 256, 0, stream>>>(BW, BW + BW_STRIDE / 2, BW + BW_STRIDE,
                                      w_re, w_im, 786432);
    // 2. in-projection: 3 Karatsuba GEMMs (K=1024) in one pipelined dispatch
    //    768 blocks x 256 threads (256x192 tiles, 4 fat waves) = 3 clean CU-rounds
    k_gemm_proj<<<768, 256, 0, stream>>>(AK, BW, PT);
    // 3. qkv repack: T1,T2,T3 -> complex proj (+bias, q scaling, k-combine, v transpose)
    dim3 gp(16, 64);
    k_pack_qk<<<gp, 256, 0, stream>>>(PT, PT + PT_STRIDE / 2, PT + PT_STRIDE,
                                      b_re, b_im, AQ, BK, BV);
    // 4. QK^T (re+im fused into one real GEMM) + min/max partials
    dim3 g2(8, 8, 64);
    k_gemm_qk<<<g2, 256, 0, stream>>>(AQ, BK, AWR, PMIN, PMAX);
    // 5. scalar reduce + v column sums; pack out-proj operands into dead BK
    k_minmax<<<1, 256, 0, stream>>>(PMIN, PMAX, 4096, SCAL);
    k_colsum<<<2048, 256, 0, stream>>>(BV, CSUM);
    k_pack2<<<1024, 256, 0, stream>>>(BORE, ow_re, ow_im, -1.f, 262144);
    k_pack2<<<1024, 256, 0, stream>>>(BOIM, ow_im, ow_re,  1.f, 262144);
    // 6. attention x V with affine (min-max) correction in epilogue (AATTN over dead AQ)
    dim3 g3(1, 8, 64);
    k_gemm_attn<<<g3, 256, 0, stream>>>(AWR, BV, AATTN, SCAL, CSUM);
    // 7. out-projection -> d_out (re, im) as one z=2 dispatch (512 blocks)
    dim3 g4(8, 32, 2);
    k_gemm_out2<<<g4, 256, 0, stream>>>(AATTN, BORE, BOIM, (float*)d_out, ob_re, ob_im);
    // 8. head-averaged attention map
    k_awavg<<<2048, 256, 0, stream>>>(AWR, SCAL, (float*)d_out + 8388608);
}

// Round 6
// 385.524 us; speedup vs baseline: 1.0560x; 1.0560x over previous
//
#include <hip/hip_runtime.h>

// Complex MHA: T=1024, B=4, E=1024, H=16, HD=64.  SCALING = 0.125.
// Pipeline (all GEMMs real f16 C = A * B^T, fp32 accum, MFMA 16x16x32):
//  1. pack3_all: AK0=xr, AK1=xi, AK2=xr+xi (4096x1024); BW0=wr,BW1=wi,BW2=wr+wi
//  2. proj (Karatsuba): T_z = AK_z BW_z^T (4096x3072, K=1024) — gemm2p<NR=3>,
//     256x192 tile, 8 waves, 2-phase asm-ds_read pipelined core (round-4 best:
//     91.6us, MfmaUtil 35; 4-wave variant was 94us -> reverted).
//  3. pack_qk: per bh: A_q=[qr|qi]*0.125, B_k=[kr+ki|kr-ki], B_v=[vr^T;vi^T]
//  4. qk: awr[bh] = A_q B_k^T (1024x1024, K=128) legacy core + min/max partials
//  5. small_fused (one dispatch): minmax reduce -> SCAL; colsum(Bv); pack BORE/BOIM
//  6. attn2: gemm2p<NR=2> 256x128 tile, grid 256 (1 blk/CU): acc = awr Bv^T;
//     epilogue sc*acc - sc*mn*colsum -> Aattn
//  7. out2b: gemm2p<NR=2>, K=2048, grid 256: d_out = Aattn Bo_{re,im}^T + ob
//  8. awavg: mean over h of awr, affine-corrected
// Dispatches: 13 -> 8 (est. ~130us of the 403 was inter-dispatch gap/overhead).

using half4 = __attribute__((__ext_vector_type__(4))) _Float16;
using half8 = __attribute__((__ext_vector_type__(8))) _Float16;
using f32x4 = __attribute__((__ext_vector_type__(4))) float;

// ---------------- workspace layout (bytes), total ~176.1 MiB ----------------
static constexpr size_t OFF_AWR    = 0;                         // 134217728
static constexpr size_t OFF_AQ     = 134217728;                 // 16777216
static constexpr size_t OFF_BK     = 150994944;                 // 16777216
static constexpr size_t OFF_BV     = 167772160;                 // 16777216
static constexpr size_t OFF_COLSUM = 184549376;                 // 8192*4
static constexpr size_t OFF_PMIN   = 184582144;                 // 4096*4
static constexpr size_t OFF_PMAX   = 184598528;                 // 4096*4
static constexpr size_t OFF_SCAL   = 184614912;                 // 2 floats
// lifetime overlays:
static constexpr size_t OFF_AATTN  = OFF_AQ;                    // after AQ dead
static constexpr size_t OFF_BORE   = OFF_BK;                    // after BK dead
static constexpr size_t OFF_BOIM   = OFF_BK + 4194304;
// phase-1 buffers overlay the (later-written) awr region [0, 119.5MB):
static constexpr size_t OFF_AK0    = 0;
static constexpr size_t AK_STRIDE  = 8388608;
static constexpr size_t OFF_BW0    = 25165824;
static constexpr size_t BW_STRIDE  = 6291456;
static constexpr size_t OFF_PT0    = 44040192;
static constexpr size_t PT_STRIDE  = 25165824;                  // ends 119537664

static __device__ __forceinline__ void gload_lds16(const void* g, void* l) {
    __builtin_amdgcn_global_load_lds(
        (__attribute__((address_space(1))) void*)(g),
        (__attribute__((address_space(3))) void*)(l), 16, 0, 0);
}

// raw LDS read, invisible to the compiler's waitcnt pass: caller supplies
// s_waitcnt lgkmcnt(N) + sched_barrier(0) before use (rule 18).
typedef __attribute__((address_space(3))) const _Float16 lds_cf16;
static __device__ __forceinline__ half8 ldsr_off(const _Float16* p, int imm) {
    half8 r;
    asm volatile("ds_read_b128 %0, %1 offset:%2"
                 : "=v"(r) : "v"((lds_cf16*)p), "i"(imm));
    return r;
}

// ============ generalized 2-phase asm-ds_read pipelined core ============
// Tile 256(M) x 64*NR(N), BK=64, 512 threads = 8 waves (2M x 4N),
// per-wave output 128 x 16*NR -> acc[8][NR].
// LDS: dbuf As[2][256][64] (64KiB) + Bs[2][64*NR][64]; xor swizzle slot=chunk^(row&7).
// Staging: 64-row units, 1 gload_lds16/thread/unit; A0..A3, B0..NR-1 per K-tile.
// Per K-tile t (buf bb=t&1, nb=bb^1), 2 barriers:
//   [issue 2NR+16 asm ds_reads: fB(2NR), fA m0..3(8), fA m4..7(8)]
//   [stage t+1-late: A1,A3 -> nb]
//   lgkmcnt(8) (fB+fA03 done; fA47 serviced under MFMA0); 8NR MFMA (m0..3)
//   s_barrier; [stage t+2-early: B0..NR-1, A0,A2 -> bb]
//   lgkmcnt(0); 8NR MFMA (m4..7); vmcnt(NR+2) steady / vmcnt(0) at t=NT-2; s_barrier
// Ledger (any NR): ph0 reads cover exactly bb{all B, A0(wr0 rows0-63), A2(wr1
// 128-191)}, completed by lgkm(8) before mid barrier -> ph1 restage SAFE.
// fA47 (bb A1,A3) disjoint from ph1 stages. nb A1,A3 last read t-1.ph1 (lgkm(0)
// + barrier) SAFE. vmcnt(NR+2) at end of t: outstanding = [t-1.ph1: NR+2]
// [t.ph0: 2][t.ph1: NR+2]; wait->NR+2 completes first NR+4 = ALL of t+1.
// Prologue: NR+4 (t0) + NR+2 (t1-early) issued; wait->NR+2 = t0 landed.
template <int NR, int NT>
__device__ __forceinline__ void gemm2p(const _Float16* __restrict__ A,
                                       const _Float16* __restrict__ B,
                                       int lda, int ldb, f32x4 acc[8][NR]) {
    __shared__ _Float16 As[2 * 256 * 64];
    __shared__ _Float16 Bs[2 * 64 * NR * 64];
    constexpr int BBUF = 64 * NR * 64;       // halfs per B buffer

    const int tid  = threadIdx.x;
    const int lane = tid & 63;
    const int w    = tid >> 6;               // 0..7
    const int wr   = w >> 2, wc = w & 3;     // 2 x 4 wave grid
    const int quad = lane >> 4, l16 = lane & 15;
    const int rowoff = tid >> 3;             // 0..63 : row within a 64-row unit
    const int chunk8 = ((tid & 7) ^ (rowoff & 7)) << 3;  // pre-swizzled chunk
    const int rsw = l16 & 7;
    const int s0  = (quad ^ rsw) << 3;       // k-window [0,32)
    const int s1  = ((quad | 4) ^ rsw) << 3; // k-window [32,64)
    const int abase = ((wr << 7) + l16) << 6;
    const int bbase = (wc * (16 * NR) + l16) << 6;

    const _Float16* Ast = A + (size_t)rowoff * lda + chunk8;
    const _Float16* Bst = B + (size_t)rowoff * ldb + chunk8;
    _Float16* Alds = As;
    _Float16* Blds = Bs;

    auto stA = [&](int buf, int u, int kt) {
        gload_lds16(Ast + (size_t)(u * 64) * lda + kt,
                    Alds + buf * 16384 + (((u << 6) + (w << 3)) << 6));
    };
    auto stB = [&](int buf, int u, int kt) {
        gload_lds16(Bst + (size_t)(u * 64) * ldb + kt,
                    Blds + buf * BBUF + (((u << 6) + (w << 3)) << 6));
    };

    #pragma unroll
    for (int i = 0; i < 8; i++)
        #pragma unroll
        for (int j = 0; j < NR; j++) acc[i][j] = (f32x4){0.f, 0.f, 0.f, 0.f};

    // prologue: tile0 all NR+4 units, then tile1-early {B0..NR-1, A0, A2}
    #pragma unroll
    for (int u = 0; u < NR; u++) stB(0, u, 0);
    #pragma unroll
    for (int u = 0; u < 4; u++) stA(0, u, 0);
    #pragma unroll
    for (int u = 0; u < NR; u++) stB(1, u, 64);
    stA(1, 0, 64); stA(1, 2, 64);
    asm volatile("s_waitcnt vmcnt(%0)" :: "i"(NR + 2) : "memory");
    __builtin_amdgcn_sched_barrier(0);
    __builtin_amdgcn_s_barrier();

    #pragma unroll 1
    for (int t = 0; t < NT; ++t) {
        const int bb = t & 1, nb = bb ^ 1;
        const int kt = t << 6;
        const _Float16* pAb = Alds + bb * 16384;
        const _Float16* pBb = Blds + bb * BBUF;
        const bool p1 = (t + 1 < NT), p2 = (t + 2 < NT);
        const _Float16* aA0 = pAb + abase + s0;
        const _Float16* aA1 = pAb + abase + s1;
        const _Float16* aB0 = pBb + bbase + s0;
        const _Float16* aB1 = pBb + bbase + s1;
        half8 fB[NR][2], fA[8][2];
        // ---- issue fB(2NR) + fA m0..3 (8) first (awaited by lgkmcnt(8)) ----
        #pragma unroll
        for (int n = 0; n < NR; n++) {
            fB[n][0] = ldsr_off(aB0, n * 2048);
            fB[n][1] = ldsr_off(aB1, n * 2048);
        }
        #pragma unroll
        for (int i = 0; i < 4; i++) {
            fA[i][0] = ldsr_off(aA0, i * 2048);
            fA[i][1] = ldsr_off(aA1, i * 2048);
        }
        // ---- then fA m4..7 (8): left in flight across MFMA0 ----
        #pragma unroll
        for (int i = 4; i < 8; i++) {
            fA[i][0] = ldsr_off(aA0, i * 2048);
            fA[i][1] = ldsr_off(aA1, i * 2048);
        }
        if (p1) { stA(nb, 1, kt + 64); stA(nb, 3, kt + 64); }
        asm volatile("s_waitcnt lgkmcnt(8)" ::: "memory");
        __builtin_amdgcn_sched_barrier(0);
        __builtin_amdgcn_s_setprio(1);
        #pragma unroll
        for (int i = 0; i < 4; i++)
            #pragma unroll
            for (int n = 0; n < NR; n++) {
                acc[i][n] = __builtin_amdgcn_mfma_f32_16x16x32_f16(fA[i][0], fB[n][0], acc[i][n], 0, 0, 0);
                acc[i][n] = __builtin_amdgcn_mfma_f32_16x16x32_f16(fA[i][1], fB[n][1], acc[i][n], 0, 0, 0);
            }
        __builtin_amdgcn_s_setprio(0);
        __builtin_amdgcn_s_barrier();
        // ---- stage t+2-early into bb (regions fully consumed), MFMA m4..7 ----
        if (p2) {
            #pragma unroll
            for (int u = 0; u < NR; u++) stB(bb, u, kt + 128);
            stA(bb, 0, kt + 128); stA(bb, 2, kt + 128);
        }
        asm volatile("s_waitcnt lgkmcnt(0)" ::: "memory");
        __builtin_amdgcn_sched_barrier(0);
        __builtin_amdgcn_s_setprio(1);
        #pragma unroll
        for (int i = 0; i < 4; i++)
            #pragma unroll
            for (int n = 0; n < NR; n++) {
                acc[i + 4][n] = __builtin_amdgcn_mfma_f32_16x16x32_f16(fA[i + 4][0], fB[n][0], acc[i + 4][n], 0, 0, 0);
                acc[i + 4][n] = __builtin_amdgcn_mfma_f32_16x16x32_f16(fA[i + 4][1], fB[n][1], acc[i + 4][n], 0, 0, 0);
            }
        __builtin_amdgcn_s_setprio(0);
        if (p2)      { asm volatile("s_waitcnt vmcnt(%0)" :: "i"(NR + 2) : "memory"); }
        else if (p1) { asm volatile("s_waitcnt vmcnt(0)" ::: "memory"); }
        __builtin_amdgcn_sched_barrier(0);
        __builtin_amdgcn_s_barrier();
    }
}

// ---------------- legacy GEMM core: 128x128 tile, BK=64, 4 waves ----------------
// (used by qk only: K=128 -> deep pipeline can't fill)
__device__ __forceinline__ void gemm_core(const _Float16* __restrict__ A,
                                          const _Float16* __restrict__ B,
                                          int K, int lda, int ldb,
                                          f32x4 acc[4][4]) {
    __shared__ _Float16 As[128 * 64];
    __shared__ _Float16 Bs[128 * 64];
    const int tid  = threadIdx.x;
    const int lane = tid & 63;
    const int w    = tid >> 6;
    const int wr   = w >> 1, wc = w & 1;
    const int quad = lane >> 4, l16 = lane & 15;
    const int grow = lane >> 3;
    const int gcol = ((lane & 7) ^ grow) * 8;
    const _Float16* apw = A + (size_t)(w * 32 + grow) * lda + gcol;
    const _Float16* bpw = B + (size_t)(w * 32 + grow) * ldb + gcol;
    _Float16* lAw = &As[(w * 32) * 64];
    _Float16* lBw = &Bs[(w * 32) * 64];

    #pragma unroll
    for (int i = 0; i < 4; i++)
        #pragma unroll
        for (int j = 0; j < 4; j++) acc[i][j] = (f32x4){0.f, 0.f, 0.f, 0.f};

    const int rsw = l16 & 7;
    const int s0  = (quad ^ rsw) * 8;
    const int s1  = ((quad | 4) ^ rsw) * 8;
    for (int kt = 0; kt < K; kt += 64) {
        #pragma unroll
        for (int i = 0; i < 4; i++) {
            gload_lds16(apw + (size_t)(i * 8) * lda + kt, lAw + i * 512);
            gload_lds16(bpw + (size_t)(i * 8) * ldb + kt, lBw + i * 512);
        }
        __syncthreads();
        half8 af0[4], af1[4], bf0[4], bf1[4];
        #pragma unroll
        for (int i = 0; i < 4; i++) {
            const int row = (wr * 64 + i * 16 + l16) * 64;
            af0[i] = *(const half8*)(&As[row + s0]);
            af1[i] = *(const half8*)(&As[row + s1]);
        }
        #pragma unroll
        for (int j = 0; j < 4; j++) {
            const int row = (wc * 64 + j * 16 + l16) * 64;
            bf0[j] = *(const half8*)(&Bs[row + s0]);
            bf1[j] = *(const half8*)(&Bs[row + s1]);
        }
        #pragma unroll
        for (int i = 0; i < 4; i++)
            #pragma unroll
            for (int j = 0; j < 4; j++) {
                acc[i][j] = __builtin_amdgcn_mfma_f32_16x16x32_f16(af0[i], bf0[j], acc[i][j], 0, 0, 0);
                acc[i][j] = __builtin_amdgcn_mfma_f32_16x16x32_f16(af1[i], bf1[j], acc[i][j], 0, 0, 0);
            }
        __syncthreads();
    }
}

// ---------------- kernels ----------------

// merged Karatsuba operand packing (one dispatch): bid<4096 -> AK job, else BW
__global__ __launch_bounds__(256) void k_pack3_all(_Float16* __restrict__ AK,
                                                   _Float16* __restrict__ BW,
                                                   const float* __restrict__ x_re,
                                                   const float* __restrict__ x_im,
                                                   const float* __restrict__ w_re,
                                                   const float* __restrict__ w_im) {
    int bid = blockIdx.x;
    _Float16* d0; const float *s1, *s2; int i4;
    if (bid < 4096) {
        d0 = AK; s1 = x_re; s2 = x_im;
        i4 = bid * 256 + threadIdx.x;                 // < 1048576 exact
        size_t idx = (size_t)i4 << 2;
        f32x4 a = *(const f32x4*)(s1 + idx);
        f32x4 b = *(const f32x4*)(s2 + idx);
        half4 h0, h1, h2;
        #pragma unroll
        for (int e = 0; e < 4; e++) {
            h0[e] = (_Float16)a[e]; h1[e] = (_Float16)b[e]; h2[e] = (_Float16)(a[e] + b[e]);
        }
        *(half4*)(d0 + idx) = h0;
        *(half4*)(d0 + (AK_STRIDE / 2) + idx) = h1;
        *(half4*)(d0 + AK_STRIDE + idx) = h2;
    } else {
        d0 = BW; s1 = w_re; s2 = w_im;
        i4 = (bid - 4096) * 256 + threadIdx.x;        // < 786432 exact
        size_t idx = (size_t)i4 << 2;
        f32x4 a = *(const f32x4*)(s1 + idx);
        f32x4 b = *(const f32x4*)(s2 + idx);
        half4 h0, h1, h2;
        #pragma unroll
        for (int e = 0; e < 4; e++) {
            h0[e] = (_Float16)a[e]; h1[e] = (_Float16)b[e]; h2[e] = (_Float16)(a[e] + b[e]);
        }
        *(half4*)(d0 + idx) = h0;
        *(half4*)(d0 + (BW_STRIDE / 2) + idx) = h1;
        *(half4*)(d0 + BW_STRIDE + idx) = h2;
    }
}

// proj: gemm2p<3,16>, 256x192 tile. grid 768 = 16(M) x 16(N) x 3(z), XCD swizzle.
__global__ __launch_bounds__(512, 2) void k_gemm_proj(const _Float16* __restrict__ AK,
                                                      const _Float16* __restrict__ BW,
                                                      _Float16* __restrict__ PT) {
    const int bid = blockIdx.x;
    const int wg  = (bid & 7) * 96 + (bid >> 3);   // bijective (768 = 8*96)
    const int z   = wg >> 8;
    const int rem = wg & 255;
    const int my  = rem >> 4, nx = rem & 15;

    const _Float16* A = AK + (size_t)z * (AK_STRIDE / 2) + ((size_t)my << 18);
    const _Float16* B = BW + (size_t)z * (BW_STRIDE / 2) + (size_t)nx * 196608;
    _Float16*       C = PT + (size_t)z * (PT_STRIDE / 2);

    f32x4 acc[8][3];
    gemm2p<3, 16>(A, B, 1024, 1024, acc);

    const int lane = threadIdx.x & 63;
    const int w    = threadIdx.x >> 6;
    const int wr   = w >> 2, wc = w & 3;
    const int quad = lane >> 4, l16 = lane & 15;
    const int m0 = my << 8, n0 = nx * 192;
    #pragma unroll
    for (int m = 0; m < 8; m++)
        #pragma unroll
        for (int n = 0; n < 3; n++)
            #pragma unroll
            for (int r = 0; r < 4; r++) {
                int row = m0 + wr * 128 + m * 16 + quad * 4 + r;
                int col = n0 + wc * 48 + n * 16 + l16;
                C[(size_t)row * 3072 + col] = (_Float16)acc[m][n][r];
            }
}

// per (bh, 64-t slab): combine T1,T2,T3 -> q,k,v; build Aq, Bk, Bv (transposed)
__global__ __launch_bounds__(256) void k_pack_qk(const _Float16* __restrict__ T1,
                                                 const _Float16* __restrict__ T2,
                                                 const _Float16* __restrict__ T3,
                                                 const float* __restrict__ b_re,
                                                 const float* __restrict__ b_im,
                                                 _Float16* __restrict__ Aq,
                                                 _Float16* __restrict__ Bk,
                                                 _Float16* __restrict__ Bv) {
    __shared__ _Float16 vt[128 * 66];
    const int bh = blockIdx.y, t0 = blockIdx.x * 64;
    const int b = bh >> 4, h = bh & 15;
    const int tid = threadIdx.x;
    const int hd = tid & 63, tg = tid >> 6;
    const int e = h * 64 + hd;
    for (int pass = 0; pass < 16; pass++) {
        int tloc = pass * 4 + tg;
        int t = t0 + tloc;
        size_t mrow = (size_t)(t * 4 + b) * 3072;
        float q1 = (float)T1[mrow + e], q2 = (float)T2[mrow + e], q3 = (float)T3[mrow + e];
        float k1 = (float)T1[mrow + 1024 + e], k2 = (float)T2[mrow + 1024 + e], k3 = (float)T3[mrow + 1024 + e];
        float v1 = (float)T1[mrow + 2048 + e], v2 = (float)T2[mrow + 2048 + e], v3 = (float)T3[mrow + 2048 + e];
        float qr = q1 - q2 + b_re[e];
        float qi = q3 - q1 - q2 + b_im[e];
        float kr = k1 - k2 + b_re[1024 + e];
        float ki = k3 - k1 - k2 + b_im[1024 + e];
        float vr = v1 - v2 + b_re[2048 + e];
        float vi = v3 - v1 - v2 + b_im[2048 + e];
        size_t qbase = ((size_t)bh * 1024 + t) * 128;
        Aq[qbase + hd]      = (_Float16)(qr * 0.125f);
        Aq[qbase + 64 + hd] = (_Float16)(qi * 0.125f);
        Bk[qbase + hd]      = (_Float16)(kr + ki);
        Bk[qbase + 64 + hd] = (_Float16)(kr - ki);
        vt[hd * 66 + tloc]        = (_Float16)vr;
        vt[(64 + hd) * 66 + tloc] = (_Float16)vi;
    }
    __syncthreads();
    size_t vbase = (size_t)bh * 131072;
    const int j = tid & 3;
    #pragma unroll
    for (int half_ = 0; half_ < 2; half_++) {
        int r = (tid >> 2) + half_ * 64;
        _Float16* dst = Bv + vbase + (size_t)r * 1024 + t0 + j * 16;
        const _Float16* src = &vt[r * 66 + j * 16];
        *(half8*)dst       = *(const half8*)src;
        *(half8*)(dst + 8) = *(const half8*)(src + 8);
    }
}

__global__ __launch_bounds__(256) void k_gemm_qk(const _Float16* __restrict__ Aq,
                                                 const _Float16* __restrict__ Bk,
                                                 _Float16* __restrict__ awr,
                                                 float* __restrict__ pmin,
                                                 float* __restrict__ pmax) {
    const int bh = blockIdx.z;
    const int m0 = blockIdx.y * 128, n0 = blockIdx.x * 128;
    f32x4 acc[4][4];
    gemm_core(Aq + (size_t)bh * 131072 + (size_t)m0 * 128,
              Bk + (size_t)bh * 131072 + (size_t)n0 * 128, 128, 128, 128, acc);
    const int lane = threadIdx.x & 63;
    const int w    = threadIdx.x >> 6;
    const int wr   = w >> 1, wc = w & 1;
    const int quad = lane >> 4, l16 = lane & 15;
    _Float16* C = awr + ((size_t)bh << 20);
    float tmn = 3.0e38f, tmx = -3.0e38f;
    #pragma unroll
    for (int i = 0; i < 4; i++)
        #pragma unroll
        for (int j = 0; j < 4; j++)
            #pragma unroll
            for (int r = 0; r < 4; r++) {
                float v = acc[i][j][r];
                tmn = fminf(tmn, v); tmx = fmaxf(tmx, v);
                int m = m0 + wr * 64 + i * 16 + quad * 4 + r;
                int n = n0 + wc * 64 + j * 16 + l16;
                C[((size_t)m << 10) + n] = (_Float16)v;
            }
    __shared__ float smn[256], smx[256];
    int tid = threadIdx.x;
    smn[tid] = tmn; smx[tid] = tmx;
    __syncthreads();
    for (int s = 128; s > 0; s >>= 1) {
        if (tid < s) { smn[tid] = fminf(smn[tid], smn[tid + s]); smx[tid] = fmaxf(smx[tid], smx[tid + s]); }
        __syncthreads();
    }
    if (tid == 0) {
        int bid = (blockIdx.z * gridDim.y + blockIdx.y) * gridDim.x + blockIdx.x;
        pmin[bid] = smn[0]; pmax[bid] = smx[0];
    }
}

// fused small work (one dispatch; jobs independent, inputs all ready):
//  bid<2048: colsum rows; 2048..3071: pack BORE=[owr|-owi]; 3072..4095:
//  pack BOIM=[owi|owr]; bid==4096: global minmax reduce -> SCAL
__global__ __launch_bounds__(256) void k_small_fused(const float* __restrict__ pmin,
                                                     const float* __restrict__ pmax,
                                                     float* __restrict__ scal,
                                                     const _Float16* __restrict__ Bv,
                                                     float* __restrict__ colsum,
                                                     _Float16* __restrict__ BORE,
                                                     _Float16* __restrict__ BOIM,
                                                     const float* __restrict__ ow_re,
                                                     const float* __restrict__ ow_im) {
    const int bid = blockIdx.x;
    const int tid = threadIdx.x;
    if (bid < 2048) {                      // colsum
        int row  = bid * 4 + (tid >> 6);
        int lane = tid & 63;
        const _Float16* p = Bv + (size_t)row * 1024;
        float s = 0.f;
        for (int i = lane; i < 1024; i += 64) s += (float)p[i];
        #pragma unroll
        for (int off = 32; off > 0; off >>= 1) s += __shfl_down(s, off, 64);
        if (lane == 0) colsum[row] = s;
    } else if (bid < 4096) {               // pack2 x2
        _Float16* dst; const float *s1, *s2; float sgn2;
        int i4;
        if (bid < 3072) { dst = BORE; s1 = ow_re; s2 = ow_im; sgn2 = -1.f; i4 = (bid - 2048) * 256 + tid; }
        else            { dst = BOIM; s1 = ow_im; s2 = ow_re; sgn2 =  1.f; i4 = (bid - 3072) * 256 + tid; }
        int r = i4 >> 8, c4 = (i4 & 255) << 2;
        size_t src = ((size_t)r << 10) + c4;
        f32x4 a = *(const f32x4*)(s1 + src);
        f32x4 b = *(const f32x4*)(s2 + src);
        half4 ha, hb;
        #pragma unroll
        for (int e = 0; e < 4; e++) { ha[e] = (_Float16)a[e]; hb[e] = (_Float16)(sgn2 * b[e]); }
        size_t o = ((size_t)r << 11) + c4;
        *(half4*)(dst + o)        = ha;
        *(half4*)(dst + o + 1024) = hb;
    } else {                               // minmax (1 block)
        __shared__ float smn[256], smx[256];
        float mn = 3.0e38f, mx = -3.0e38f;
        for (int i = tid; i < 4096; i += 256) { mn = fminf(mn, pmin[i]); mx = fmaxf(mx, pmax[i]); }
        smn[tid] = mn; smx[tid] = mx;
        __syncthreads();
        for (int s = 128; s > 0; s >>= 1) {
            if (tid < s) { smn[tid] = fminf(smn[tid], smn[tid + s]); smx[tid] = fmaxf(smx[tid], smx[tid + s]); }
            __syncthreads();
        }
        if (tid == 0) { scal[0] = smn[0]; scal[1] = 1.0f / (smx[0] - smn[0]); }
    }
}

// attn: gemm2p<2,16>, 256x128 tile per (bh, m-block). grid 256 = 1 blk/CU.
__global__ __launch_bounds__(512, 2) void k_gemm_attn2(const _Float16* __restrict__ awr,
                                                       const _Float16* __restrict__ Bv,
                                                       _Float16* __restrict__ Aattn,
                                                       const float* __restrict__ scal,
                                                       const float* __restrict__ colsum) {
    const int bid = blockIdx.x;
    const int wg  = (bid & 7) * 32 + (bid >> 3);   // bijective (256 = 8*32)
    const int bh  = wg >> 2, mb = wg & 3;
    const int m0  = mb * 256;
    f32x4 acc[8][2];
    gemm2p<2, 16>(awr + ((size_t)bh << 20) + (size_t)m0 * 1024,
                  Bv + (size_t)bh * 131072, 1024, 1024, acc);
    const int lane = threadIdx.x & 63;
    const int w    = threadIdx.x >> 6;
    const int wr   = w >> 2, wc = w & 3;
    const int quad = lane >> 4, l16 = lane & 15;
    const float sc = scal[1];
    const float c0 = sc * scal[0];
    const int b = bh >> 4, h = bh & 15;
    #pragma unroll
    for (int m = 0; m < 8; m++)
        #pragma unroll
        for (int j = 0; j < 2; j++)
            #pragma unroll
            for (int r = 0; r < 4; r++) {
                int mm = m0 + wr * 128 + m * 16 + quad * 4 + r;  // q position
                int n  = wc * 32 + j * 16 + l16;                 // 0..127
                float v = sc * acc[m][j][r] - c0 * colsum[bh * 128 + n];
                int e = (n < 64) ? (h * 64 + n) : (1024 + h * 64 + n - 64);
                Aattn[(size_t)(mm * 4 + b) * 2048 + e] = (_Float16)v;
            }
}

// out-projection: gemm2p<2,32>, 256x128 tile, K=2048. grid 256 = 16my x 8nx x 2z.
__global__ __launch_bounds__(512, 2) void k_gemm_out2b(const _Float16* __restrict__ A,
                                                       const _Float16* __restrict__ Bre,
                                                       const _Float16* __restrict__ Bim,
                                                       float* __restrict__ outp,
                                                       const float* __restrict__ ob_re,
                                                       const float* __restrict__ ob_im) {
    const int bid = blockIdx.x;
    const int wg  = (bid & 7) * 32 + (bid >> 3);   // bijective (256 = 8*32)
    const int my  = wg >> 4;
    const int nxz = wg & 15;
    const int z   = nxz >> 3, nx = nxz & 7;
    const _Float16* B = z ? Bim : Bre;
    const float* bias = z ? ob_im : ob_re;
    float* out = outp + (size_t)z * 4194304;
    const int m0 = my * 256, n0 = nx * 128;
    f32x4 acc[8][2];
    gemm2p<2, 32>(A + (size_t)m0 * 2048, B + (size_t)n0 * 2048, 2048, 2048, acc);
    const int lane = threadIdx.x & 63;
    const int w    = threadIdx.x >> 6;
    const int wr   = w >> 2, wc = w & 3;
    const int quad = lane >> 4, l16 = lane & 15;
    #pragma unroll
    for (int m = 0; m < 8; m++)
        #pragma unroll
        for (int j = 0; j < 2; j++)
            #pragma unroll
            for (int r = 0; r < 4; r++) {
                int mm = m0 + wr * 128 + m * 16 + quad * 4 + r;
                int nn = n0 + wc * 32 + j * 16 + l16;
                out[((size_t)mm << 10) + nn] = acc[m][j][r] + bias[nn];
            }
}

__global__ __launch_bounds__(256) void k_awavg(const _Float16* __restrict__ awr,
                                               const float* __restrict__ scal,
                                               float* __restrict__ out) {
    int i = blockIdx.x * 256 + threadIdx.x;
    int k = (i & 127) * 8, q = (i >> 7) & 1023, b = i >> 17;
    float s[8] = {0, 0, 0, 0, 0, 0, 0, 0};
    size_t base = ((size_t)b << 24) + ((size_t)q << 10) + k;
    #pragma unroll
    for (int h = 0; h < 16; h++) {
        half8 v = *(const half8*)(awr + base + ((size_t)h << 20));
        #pragma unroll
        for (int e = 0; e < 8; e++) s[e] += (float)v[e];
    }
    const float mn = scal[0], sc = scal[1];
    float* dst = out + ((size_t)b << 20) + ((size_t)q << 10) + k;
    f32x4 o0, o1;
    #pragma unroll
    for (int e = 0; e < 4; e++) o0[e] = (s[e] * 0.0625f - mn) * sc;
    #pragma unroll
    for (int e = 0; e < 4; e++) o1[e] = (s[4 + e] * 0.0625f - mn) * sc;
    *(f32x4*)dst = o0;
    *(f32x4*)(dst + 4) = o1;
}

extern "C" void kernel_launch(void* const* d_in, const int* in_sizes, int n_in,
                              void* d_out, int out_size, void* d_ws, size_t ws_size,
                              hipStream_t stream) {
    const float* x_re  = (const float*)d_in[0];
    const float* x_im  = (const float*)d_in[1];
    const float* w_re  = (const float*)d_in[2];
    const float* w_im  = (const float*)d_in[3];
    const float* b_re  = (const float*)d_in[4];
    const float* b_im  = (const float*)d_in[5];
    const float* ow_re = (const float*)d_in[6];
    const float* ow_im = (const float*)d_in[7];
    const float* ob_re = (const float*)d_in[8];
    const float* ob_im = (const float*)d_in[9];

    char* ws = (char*)d_ws;
    _Float16* AWR   = (_Float16*)(ws + OFF_AWR);
    _Float16* AQ    = (_Float16*)(ws + OFF_AQ);
    _Float16* BK    = (_Float16*)(ws + OFF_BK);
    _Float16* BV    = (_Float16*)(ws + OFF_BV);
    _Float16* AATTN = (_Float16*)(ws + OFF_AATTN);
    _Float16* BORE  = (_Float16*)(ws + OFF_BORE);
    _Float16* BOIM  = (_Float16*)(ws + OFF_BOIM);
    float*    CSUM  = (float*)(ws + OFF_COLSUM);
    float*    PMIN  = (float*)(ws + OFF_PMIN);
    float*    PMAX  = (float*)(ws + OFF_PMAX);
    float*    SCAL  = (float*)(ws + OFF_SCAL);
    _Float16* AK    = (_Float16*)(ws + OFF_AK0);
    _Float16* BW    = (_Float16*)(ws + OFF_BW0);
    _Float16* PT    = (_Float16*)(ws + OFF_PT0);

    // 1. Karatsuba operand packing (one dispatch)
    k_pack3_all<<<7168, 256, 0, stream>>>(AK, BW, x_re, x_im, w_re, w_im);
    // 2. in-projection: 3 Karatsuba GEMMs (K=1024), 768 blocks x 512 thr
    k_gemm_proj<<<768, 512, 0, stream>>>(AK, BW, PT);
    // 3. qkv repack
    dim3 gp(16, 64);
    k_pack_qk<<<gp, 256, 0, stream>>>(PT, PT + PT_STRIDE / 2, PT + PT_STRIDE,
                                      b_re, b_im, AQ, BK, BV);
    // 4. QK^T (re+im fused into one real GEMM) + min/max partials
    dim3 g2(8, 8, 64);
    k_gemm_qk<<<g2, 256, 0, stream>>>(AQ, BK, AWR, PMIN, PMAX);
    // 5. fused small work: minmax + colsum + out-proj operand packing
    k_small_fused<<<4097, 256, 0, stream>>>(PMIN, PMAX, SCAL, BV, CSUM,
                                            BORE, BOIM, ow_re, ow_im);
    // 6. attention x V with affine correction (256 blocks, pipelined core)
    k_gemm_attn2<<<256, 512, 0, stream>>>(AWR, BV, AATTN, SCAL, CSUM);
    // 7. out-projection (256 blocks, K=2048, pipelined core)
    k_gemm_out2b<<<256, 512, 0, stream>>>(AATTN, BORE, BOIM, (float*)d_out,
                                          ob_re, ob_im);
    // 8. head-averaged attention map
    k_awavg<<<2048, 256, 0, stream>>>(AWR, SCAL, (float*)d_out + 8388608);
}

// Round 8
// 384.029 us; speedup vs baseline: 1.0601x; 1.0039x over previous
//
#include <hip/hip_runtime.h>

// Complex MHA: T=1024, B=4, E=1024, H=16, HD=64.  SCALING = 0.125.
// Pipeline (all GEMMs real f16 C = A * B^T, fp32 accum, MFMA 16x16x32):
//  1. pack3_all: AK0=xr, AK1=xi, AK2=xr+xi (4096x1024); BW0=wr,BW1=wi,BW2=wr+wi
//  2. proj (Karatsuba): T_z = AK_z BW_z^T (4096x3072, K=1024) — gemm2p<NR=3>
//  3. pack_qk: per bh: A_q=[qr|qi]*0.125, B_k=[kr+ki|kr-ki], B_v=[vr^T;vi^T]
//  4. qk: awr[bh] = A_q B_k^T (1024x1024, K=128) legacy core + min/max partials
//  5. small_fused: minmax reduce -> SCAL; colsum(Bv); pack BORE/BOIM
//  6. attn2: gemm2p<NR=2>: acc = awr Bv^T; epilogue sc*acc - sc*mn*colsum
//  7. out2b: gemm2p<NR=2>, K=2048: d_out = Aattn Bo_{re,im}^T + ob
//  8. awavg: mean over h of awr, affine-corrected
//
// gemm2p core history: 2-phase asm-ds_read (r4: 91.6us proj, MfmaUtil 35; r6:
// 88.8us/37%).  r7 change: ** fine read||MFMA interleave ** — the old schedule
// convoyed (post-barrier, all 8 waves burst 14 reads ~1344cy LDS service with
// MFMA idle, then 931cy MFMA with LDS idle).  Now 5 MFMA groups per K-tile
// (k-half split), each gated by an exact counted lgkmcnt, reads issued 1-2
// groups ahead -> LDS service hides under MFMA.  Same 2-barrier/K-tile ledger.
// NOTE r8: r7 bench died with a container-level error (same signature as r3,
// which passed on identical resubmission).  Re-audited lgkm/vmcnt ledgers,
// barrier uniformity, stage hazards, VGPR budget -> no defect; resubmitting.

using half4 = __attribute__((__ext_vector_type__(4))) _Float16;
using half8 = __attribute__((__ext_vector_type__(8))) _Float16;
using f32x4 = __attribute__((__ext_vector_type__(4))) float;

// ---------------- workspace layout (bytes), total ~176.1 MiB ----------------
static constexpr size_t OFF_AWR    = 0;                         // 134217728
static constexpr size_t OFF_AQ     = 134217728;                 // 16777216
static constexpr size_t OFF_BK     = 150994944;                 // 16777216
static constexpr size_t OFF_BV     = 167772160;                 // 16777216
static constexpr size_t OFF_COLSUM = 184549376;                 // 8192*4
static constexpr size_t OFF_PMIN   = 184582144;                 // 4096*4
static constexpr size_t OFF_PMAX   = 184598528;                 // 4096*4
static constexpr size_t OFF_SCAL   = 184614912;                 // 2 floats
// lifetime overlays:
static constexpr size_t OFF_AATTN  = OFF_AQ;                    // after AQ dead
static constexpr size_t OFF_BORE   = OFF_BK;                    // after BK dead
static constexpr size_t OFF_BOIM   = OFF_BK + 4194304;
// phase-1 buffers overlay the (later-written) awr region [0, 119.5MB):
static constexpr size_t OFF_AK0    = 0;
static constexpr size_t AK_STRIDE  = 8388608;
static constexpr size_t OFF_BW0    = 25165824;
static constexpr size_t BW_STRIDE  = 6291456;
static constexpr size_t OFF_PT0    = 44040192;
static constexpr size_t PT_STRIDE  = 25165824;                  // ends 119537664

static __device__ __forceinline__ void gload_lds16(const void* g, void* l) {
    __builtin_amdgcn_global_load_lds(
        (__attribute__((address_space(1))) void*)(g),
        (__attribute__((address_space(3))) void*)(l), 16, 0, 0);
}

// raw LDS read, invisible to the compiler's waitcnt pass: caller supplies
// s_waitcnt lgkmcnt(N) + sched_barrier(0) before use (rule 18).
typedef __attribute__((address_space(3))) const _Float16 lds_cf16;
static __device__ __forceinline__ half8 ldsr_off(const _Float16* p, int imm) {
    half8 r;
    asm volatile("ds_read_b128 %0, %1 offset:%2"
                 : "=v"(r) : "v"((lds_cf16*)p), "i"(imm));
    return r;
}

#define LGKM(N) do { asm volatile("s_waitcnt lgkmcnt(%0)" :: "i"(N) : "memory"); \
                     __builtin_amdgcn_sched_barrier(0); } while (0)

// ============ 2-phase asm-ds_read pipelined core, fine interleave ============
// Tile 256(M) x 64*NR(N), BK=64, 512 threads = 8 waves (2M x 4N),
// per-wave output 128 x 16*NR -> acc[8][NR].
// LDS: dbuf As[2][256][64] (64KiB) + Bs[2][64*NR][64]; xor swizzle slot=chunk^(row&7).
// Staging: 64-row units, 1 gload_lds16/thread/unit; A0..A3, B0..NR-1 per K-tile.
// Per K-tile t (buf bb=t&1, nb=bb^1):
//   [stage t+1-late: A1,A3 -> nb]            (region last read at t-1, barrier'd)
//   issue rB0(NR) rA01k0(2) | rA23k0(2)      -> lgkm(2):   MFMA G0 = m01 k0 (2NR)
//   issue rA4..7k0(4)                        -> lgkm(4):   MFMA G1 = m23 k0 (2NR)
//   issue rB1(NR) rA0..3k1(4)                -> lgkm(NR+4):MFMA G2 = m4..7 k0 (4NR)
//   issue rA4..7k1(4)                        -> lgkm(4):   MFMA G3 = m0..3 k1 (4NR)
//                                            -> lgkm(0):   MFMA G4 = m4..7 k1 (4NR)
//   s_barrier  (all waves' reads of bb done -> restage safe)
//   [stage t+2-early: B0..NR-1, A0, A2 -> bb]
//   vmcnt(NR+2) steady / vmcnt(0) at t=NT-2; s_barrier
// vmcnt ledger (in-order): outstanding at wait = t+1-early(NR+2, end of t-1)
// + t+1-late(2, top of t) + t+2-early(NR+2) = 2NR+6; wait->NR+2 completes the
// oldest NR+4 = ALL of tile t+1.  Prologue: t0(NR+4)+t1-early(NR+2), wait->NR+2
// lands t0.  lgkm counts verified group-by-group (in-order DS completion).
template <int NR, int NT>
__device__ __forceinline__ void gemm2p(const _Float16* __restrict__ A,
                                       const _Float16* __restrict__ B,
                                       int lda, int ldb, f32x4 acc[8][NR]) {
    __shared__ _Float16 As[2 * 256 * 64];
    __shared__ _Float16 Bs[2 * 64 * NR * 64];
    constexpr int BBUF = 64 * NR * 64;       // halfs per B buffer

    const int tid  = threadIdx.x;
    const int lane = tid & 63;
    const int w    = tid >> 6;               // 0..7
    const int wr   = w >> 2, wc = w & 3;     // 2 x 4 wave grid
    const int quad = lane >> 4, l16 = lane & 15;
    const int rowoff = tid >> 3;             // 0..63 : row within a 64-row unit
    const int chunk8 = ((tid & 7) ^ (rowoff & 7)) << 3;  // pre-swizzled chunk
    const int rsw = l16 & 7;
    const int s0  = (quad ^ rsw) << 3;       // k-window [0,32)
    const int s1  = ((quad | 4) ^ rsw) << 3; // k-window [32,64)
    const int abase = ((wr << 7) + l16) << 6;
    const int bbase = (wc * (16 * NR) + l16) << 6;

    const _Float16* Ast = A + (size_t)rowoff * lda + chunk8;
    const _Float16* Bst = B + (size_t)rowoff * ldb + chunk8;
    _Float16* Alds = As;
    _Float16* Blds = Bs;

    auto stA = [&](int buf, int u, int kt) {
        gload_lds16(Ast + (size_t)(u * 64) * lda + kt,
                    Alds + buf * 16384 + (((u << 6) + (w << 3)) << 6));
    };
    auto stB = [&](int buf, int u, int kt) {
        gload_lds16(Bst + (size_t)(u * 64) * ldb + kt,
                    Blds + buf * BBUF + (((u << 6) + (w << 3)) << 6));
    };

    #pragma unroll
    for (int i = 0; i < 8; i++)
        #pragma unroll
        for (int j = 0; j < NR; j++) acc[i][j] = (f32x4){0.f, 0.f, 0.f, 0.f};

    // prologue: tile0 all NR+4 units, then tile1-early {B0..NR-1, A0, A2}
    #pragma unroll
    for (int u = 0; u < NR; u++) stB(0, u, 0);
    #pragma unroll
    for (int u = 0; u < 4; u++) stA(0, u, 0);
    #pragma unroll
    for (int u = 0; u < NR; u++) stB(1, u, 64);
    stA(1, 0, 64); stA(1, 2, 64);
    asm volatile("s_waitcnt vmcnt(%0)" :: "i"(NR + 2) : "memory");
    __builtin_amdgcn_sched_barrier(0);
    __builtin_amdgcn_s_barrier();

    #pragma unroll 1
    for (int t = 0; t < NT; ++t) {
        const int bb = t & 1, nb = bb ^ 1;
        const int kt = t << 6;
        const _Float16* pAb = Alds + bb * 16384;
        const _Float16* pBb = Blds + bb * BBUF;
        const bool p1 = (t + 1 < NT), p2 = (t + 2 < NT);
        const _Float16* aA0 = pAb + abase + s0;
        const _Float16* aA1 = pAb + abase + s1;
        const _Float16* aB0 = pBb + bbase + s0;
        const _Float16* aB1 = pBb + bbase + s1;
        half8 fB[NR][2], fA[8][2];

        // stage t+1-late early (max latency cover; region safe since t-1's end)
        if (p1) { stA(nb, 1, kt + 64); stA(nb, 3, kt + 64); }

        // ---- issue rB0(NR) + rA0,rA1 k0 ----
        #pragma unroll
        for (int n = 0; n < NR; n++) fB[n][0] = ldsr_off(aB0, n * 2048);
        fA[0][0] = ldsr_off(aA0, 0);
        fA[1][0] = ldsr_off(aA0, 2048);
        // ---- issue rA2,rA3 k0 ----
        fA[2][0] = ldsr_off(aA0, 4096);
        fA[3][0] = ldsr_off(aA0, 6144);
        LGKM(2);                                   // rB0 + rA01k0 ready
        __builtin_amdgcn_s_setprio(1);
        #pragma unroll
        for (int i = 0; i < 2; i++)
            #pragma unroll
            for (int n = 0; n < NR; n++)
                acc[i][n] = __builtin_amdgcn_mfma_f32_16x16x32_f16(fA[i][0], fB[n][0], acc[i][n], 0, 0, 0);
        // ---- issue rA4..7 k0 ----
        #pragma unroll
        for (int i = 4; i < 8; i++) fA[i][0] = ldsr_off(aA0, i * 2048);
        LGKM(4);                                   // rA23k0 ready
        #pragma unroll
        for (int i = 2; i < 4; i++)
            #pragma unroll
            for (int n = 0; n < NR; n++)
                acc[i][n] = __builtin_amdgcn_mfma_f32_16x16x32_f16(fA[i][0], fB[n][0], acc[i][n], 0, 0, 0);
        // ---- issue rB1(NR) + rA0..3 k1 ----
        #pragma unroll
        for (int n = 0; n < NR; n++) fB[n][1] = ldsr_off(aB1, n * 2048);
        #pragma unroll
        for (int i = 0; i < 4; i++) fA[i][1] = ldsr_off(aA1, i * 2048);
        LGKM(NR + 4);                              // rA4..7k0 ready
        #pragma unroll
        for (int i = 4; i < 8; i++)
            #pragma unroll
            for (int n = 0; n < NR; n++)
                acc[i][n] = __builtin_amdgcn_mfma_f32_16x16x32_f16(fA[i][0], fB[n][0], acc[i][n], 0, 0, 0);
        // ---- issue rA4..7 k1 ----
        #pragma unroll
        for (int i = 4; i < 8; i++) fA[i][1] = ldsr_off(aA1, i * 2048);
        LGKM(4);                                   // rB1 + rA0..3k1 ready
        #pragma unroll
        for (int i = 0; i < 4; i++)
            #pragma unroll
            for (int n = 0; n < NR; n++)
                acc[i][n] = __builtin_amdgcn_mfma_f32_16x16x32_f16(fA[i][1], fB[n][1], acc[i][n], 0, 0, 0);
        LGKM(0);                                   // rA4..7k1 ready
        #pragma unroll
        for (int i = 4; i < 8; i++)
            #pragma unroll
            for (int n = 0; n < NR; n++)
                acc[i][n] = __builtin_amdgcn_mfma_f32_16x16x32_f16(fA[i][1], fB[n][1], acc[i][n], 0, 0, 0);
        __builtin_amdgcn_s_setprio(0);
        __builtin_amdgcn_s_barrier();              // all waves done reading bb
        // ---- stage t+2-early into bb ----
        if (p2) {
            #pragma unroll
            for (int u = 0; u < NR; u++) stB(bb, u, kt + 128);
            stA(bb, 0, kt + 128); stA(bb, 2, kt + 128);
        }
        if (p2)      { asm volatile("s_waitcnt vmcnt(%0)" :: "i"(NR + 2) : "memory"); }
        else if (p1) { asm volatile("s_waitcnt vmcnt(0)" ::: "memory"); }
        __builtin_amdgcn_sched_barrier(0);
        __builtin_amdgcn_s_barrier();
    }
}

// ---------------- legacy GEMM core: 128x128 tile, BK=64, 4 waves ----------------
// (used by qk only: K=128 -> deep pipeline can't fill)
__device__ __forceinline__ void gemm_core(const _Float16* __restrict__ A,
                                          const _Float16* __restrict__ B,
                                          int K, int lda, int ldb,
                                          f32x4 acc[4][4]) {
    __shared__ _Float16 As[128 * 64];
    __shared__ _Float16 Bs[128 * 64];
    const int tid  = threadIdx.x;
    const int lane = tid & 63;
    const int w    = tid >> 6;
    const int wr   = w >> 1, wc = w & 1;
    const int quad = lane >> 4, l16 = lane & 15;
    const int grow = lane >> 3;
    const int gcol = ((lane & 7) ^ grow) * 8;
    const _Float16* apw = A + (size_t)(w * 32 + grow) * lda + gcol;
    const _Float16* bpw = B + (size_t)(w * 32 + grow) * ldb + gcol;
    _Float16* lAw = &As[(w * 32) * 64];
    _Float16* lBw = &Bs[(w * 32) * 64];

    #pragma unroll
    for (int i = 0; i < 4; i++)
        #pragma unroll
        for (int j = 0; j < 4; j++) acc[i][j] = (f32x4){0.f, 0.f, 0.f, 0.f};

    const int rsw = l16 & 7;
    const int s0  = (quad ^ rsw) * 8;
    const int s1  = ((quad | 4) ^ rsw) * 8;
    for (int kt = 0; kt < K; kt += 64) {
        #pragma unroll
        for (int i = 0; i < 4; i++) {
            gload_lds16(apw + (size_t)(i * 8) * lda + kt, lAw + i * 512);
            gload_lds16(bpw + (size_t)(i * 8) * ldb + kt, lBw + i * 512);
        }
        __syncthreads();
        half8 af0[4], af1[4], bf0[4], bf1[4];
        #pragma unroll
        for (int i = 0; i < 4; i++) {
            const int row = (wr * 64 + i * 16 + l16) * 64;
            af0[i] = *(const half8*)(&As[row + s0]);
            af1[i] = *(const half8*)(&As[row + s1]);
        }
        #pragma unroll
        for (int j = 0; j < 4; j++) {
            const int row = (wc * 64 + j * 16 + l16) * 64;
            bf0[j] = *(const half8*)(&Bs[row + s0]);
            bf1[j] = *(const half8*)(&Bs[row + s1]);
        }
        #pragma unroll
        for (int i = 0; i < 4; i++)
            #pragma unroll
            for (int j = 0; j < 4; j++) {
                acc[i][j] = __builtin_amdgcn_mfma_f32_16x16x32_f16(af0[i], bf0[j], acc[i][j], 0, 0, 0);
                acc[i][j] = __builtin_amdgcn_mfma_f32_16x16x32_f16(af1[i], bf1[j], acc[i][j], 0, 0, 0);
            }
        __syncthreads();
    }
}

// ---------------- kernels ----------------

// merged Karatsuba operand packing (one dispatch): bid<4096 -> AK job, else BW
__global__ __launch_bounds__(256) void k_pack3_all(_Float16* __restrict__ AK,
                                                   _Float16* __restrict__ BW,
                                                   const float* __restrict__ x_re,
                                                   const float* __restrict__ x_im,
                                                   const float* __restrict__ w_re,
                                                   const float* __restrict__ w_im) {
    int bid = blockIdx.x;
    if (bid < 4096) {
        int i4 = bid * 256 + threadIdx.x;
        size_t idx = (size_t)i4 << 2;
        f32x4 a = *(const f32x4*)(x_re + idx);
        f32x4 b = *(const f32x4*)(x_im + idx);
        half4 h0, h1, h2;
        #pragma unroll
        for (int e = 0; e < 4; e++) {
            h0[e] = (_Float16)a[e]; h1[e] = (_Float16)b[e]; h2[e] = (_Float16)(a[e] + b[e]);
        }
        *(half4*)(AK + idx) = h0;
        *(half4*)(AK + (AK_STRIDE / 2) + idx) = h1;
        *(half4*)(AK + AK_STRIDE + idx) = h2;
    } else {
        int i4 = (bid - 4096) * 256 + threadIdx.x;
        size_t idx = (size_t)i4 << 2;
        f32x4 a = *(const f32x4*)(w_re + idx);
        f32x4 b = *(const f32x4*)(w_im + idx);
        half4 h0, h1, h2;
        #pragma unroll
        for (int e = 0; e < 4; e++) {
            h0[e] = (_Float16)a[e]; h1[e] = (_Float16)b[e]; h2[e] = (_Float16)(a[e] + b[e]);
        }
        *(half4*)(BW + idx) = h0;
        *(half4*)(BW + (BW_STRIDE / 2) + idx) = h1;
        *(half4*)(BW + BW_STRIDE + idx) = h2;
    }
}

// proj: gemm2p<3,16>, 256x192 tile. grid 768 = 16(M) x 16(N) x 3(z), XCD swizzle.
__global__ __launch_bounds__(512, 2) void k_gemm_proj(const _Float16* __restrict__ AK,
                                                      const _Float16* __restrict__ BW,
                                                      _Float16* __restrict__ PT) {
    const int bid = blockIdx.x;
    const int wg  = (bid & 7) * 96 + (bid >> 3);   // bijective (768 = 8*96)
    const int z   = wg >> 8;
    const int rem = wg & 255;
    const int my  = rem >> 4, nx = rem & 15;

    const _Float16* A = AK + (size_t)z * (AK_STRIDE / 2) + ((size_t)my << 18);
    const _Float16* B = BW + (size_t)z * (BW_STRIDE / 2) + (size_t)nx * 196608;
    _Float16*       C = PT + (size_t)z * (PT_STRIDE / 2);

    f32x4 acc[8][3];
    gemm2p<3, 16>(A, B, 1024, 1024, acc);

    const int lane = threadIdx.x & 63;
    const int w    = threadIdx.x >> 6;
    const int wr   = w >> 2, wc = w & 3;
    const int quad = lane >> 4, l16 = lane & 15;
    const int m0 = my << 8, n0 = nx * 192;
    #pragma unroll
    for (int m = 0; m < 8; m++)
        #pragma unroll
        for (int n = 0; n < 3; n++)
            #pragma unroll
            for (int r = 0; r < 4; r++) {
                int row = m0 + wr * 128 + m * 16 + quad * 4 + r;
                int col = n0 + wc * 48 + n * 16 + l16;
                C[(size_t)row * 3072 + col] = (_Float16)acc[m][n][r];
            }
}

// per (bh, 64-t slab): combine T1,T2,T3 -> q,k,v; build Aq, Bk, Bv (transposed)
__global__ __launch_bounds__(256) void k_pack_qk(const _Float16* __restrict__ T1,
                                                 const _Float16* __restrict__ T2,
                                                 const _Float16* __restrict__ T3,
                                                 const float* __restrict__ b_re,
                                                 const float* __restrict__ b_im,
                                                 _Float16* __restrict__ Aq,
                                                 _Float16* __restrict__ Bk,
                                                 _Float16* __restrict__ Bv) {
    __shared__ _Float16 vt[128 * 66];
    const int bh = blockIdx.y, t0 = blockIdx.x * 64;
    const int b = bh >> 4, h = bh & 15;
    const int tid = threadIdx.x;
    const int hd = tid & 63, tg = tid >> 6;
    const int e = h * 64 + hd;
    for (int pass = 0; pass < 16; pass++) {
        int tloc = pass * 4 + tg;
        int t = t0 + tloc;
        size_t mrow = (size_t)(t * 4 + b) * 3072;
        float q1 = (float)T1[mrow + e], q2 = (float)T2[mrow + e], q3 = (float)T3[mrow + e];
        float k1 = (float)T1[mrow + 1024 + e], k2 = (float)T2[mrow + 1024 + e], k3 = (float)T3[mrow + 1024 + e];
        float v1 = (float)T1[mrow + 2048 + e], v2 = (float)T2[mrow + 2048 + e], v3 = (float)T3[mrow + 2048 + e];
        float qr = q1 - q2 + b_re[e];
        float qi = q3 - q1 - q2 + b_im[e];
        float kr = k1 - k2 + b_re[1024 + e];
        float ki = k3 - k1 - k2 + b_im[1024 + e];
        float vr = v1 - v2 + b_re[2048 + e];
        float vi = v3 - v1 - v2 + b_im[2048 + e];
        size_t qbase = ((size_t)bh * 1024 + t) * 128;
        Aq[qbase + hd]      = (_Float16)(qr * 0.125f);
        Aq[qbase + 64 + hd] = (_Float16)(qi * 0.125f);
        Bk[qbase + hd]      = (_Float16)(kr + ki);
        Bk[qbase + 64 + hd] = (_Float16)(kr - ki);
        vt[hd * 66 + tloc]        = (_Float16)vr;
        vt[(64 + hd) * 66 + tloc] = (_Float16)vi;
    }
    __syncthreads();
    size_t vbase = (size_t)bh * 131072;
    const int j = tid & 3;
    #pragma unroll
    for (int half_ = 0; half_ < 2; half_++) {
        int r = (tid >> 2) + half_ * 64;
        _Float16* dst = Bv + vbase + (size_t)r * 1024 + t0 + j * 16;
        const _Float16* src = &vt[r * 66 + j * 16];
        *(half8*)dst       = *(const half8*)src;
        *(half8*)(dst + 8) = *(const half8*)(src + 8);
    }
}

__global__ __launch_bounds__(256) void k_gemm_qk(const _Float16* __restrict__ Aq,
                                                 const _Float16* __restrict__ Bk,
                                                 _Float16* __restrict__ awr,
                                                 float* __restrict__ pmin,
                                                 float* __restrict__ pmax) {
    const int bh = blockIdx.z;
    const int m0 = blockIdx.y * 128, n0 = blockIdx.x * 128;
    f32x4 acc[4][4];
    gemm_core(Aq + (size_t)bh * 131072 + (size_t)m0 * 128,
              Bk + (size_t)bh * 131072 + (size_t)n0 * 128, 128, 128, 128, acc);
    const int lane = threadIdx.x & 63;
    const int w    = threadIdx.x >> 6;
    const int wr   = w >> 1, wc = w & 1;
    const int quad = lane >> 4, l16 = lane & 15;
    _Float16* C = awr + ((size_t)bh << 20);
    float tmn = 3.0e38f, tmx = -3.0e38f;
    #pragma unroll
    for (int i = 0; i < 4; i++)
        #pragma unroll
        for (int j = 0; j < 4; j++)
            #pragma unroll
            for (int r = 0; r < 4; r++) {
                float v = acc[i][j][r];
                tmn = fminf(tmn, v); tmx = fmaxf(tmx, v);
                int m = m0 + wr * 64 + i * 16 + quad * 4 + r;
                int n = n0 + wc * 64 + j * 16 + l16;
                C[((size_t)m << 10) + n] = (_Float16)v;
            }
    __shared__ float smn[256], smx[256];
    int tid = threadIdx.x;
    smn[tid] = tmn; smx[tid] = tmx;
    __syncthreads();
    for (int s = 128; s > 0; s >>= 1) {
        if (tid < s) { smn[tid] = fminf(smn[tid], smn[tid + s]); smx[tid] = fmaxf(smx[tid], smx[tid + s]); }
        __syncthreads();
    }
    if (tid == 0) {
        int bid = (blockIdx.z * gridDim.y + blockIdx.y) * gridDim.x + blockIdx.x;
        pmin[bid] = smn[0]; pmax[bid] = smx[0];
    }
}

// fused small work (one dispatch; jobs independent, inputs all ready):
//  bid<2048: colsum rows; 2048..3071: pack BORE=[owr|-owi]; 3072..4095:
//  pack BOIM=[owi|owr]; bid==4096: global minmax reduce -> SCAL
__global__ __launch_bounds__(256) void k_small_fused(const float* __restrict__ pmin,
                                                     const float* __restrict__ pmax,
                                                     float* __restrict__ scal,
                                                     const _Float16* __restrict__ Bv,
                                                     float* __restrict__ colsum,
                                                     _Float16* __restrict__ BORE,
                                                     _Float16* __restrict__ BOIM,
                                                     const float* __restrict__ ow_re,
                                                     const float* __restrict__ ow_im) {
    const int bid = blockIdx.x;
    const int tid = threadIdx.x;
    if (bid < 2048) {                      // colsum
        int row  = bid * 4 + (tid >> 6);
        int lane = tid & 63;
        const _Float16* p = Bv + (size_t)row * 1024;
        float s = 0.f;
        for (int i = lane; i < 1024; i += 64) s += (float)p[i];
        #pragma unroll
        for (int off = 32; off > 0; off >>= 1) s += __shfl_down(s, off, 64);
        if (lane == 0) colsum[row] = s;
    } else if (bid < 4096) {               // pack2 x2
        _Float16* dst; const float *s1, *s2; float sgn2;
        int i4;
        if (bid < 3072) { dst = BORE; s1 = ow_re; s2 = ow_im; sgn2 = -1.f; i4 = (bid - 2048) * 256 + tid; }
        else            { dst = BOIM; s1 = ow_im; s2 = ow_re; sgn2 =  1.f; i4 = (bid - 3072) * 256 + tid; }
        int r = i4 >> 8, c4 = (i4 & 255) << 2;
        size_t src = ((size_t)r << 10) + c4;
        f32x4 a = *(const f32x4*)(s1 + src);
        f32x4 b = *(const f32x4*)(s2 + src);
        half4 ha, hb;
        #pragma unroll
        for (int e = 0; e < 4; e++) { ha[e] = (_Float16)a[e]; hb[e] = (_Float16)(sgn2 * b[e]); }
        size_t o = ((size_t)r << 11) + c4;
        *(half4*)(dst + o)        = ha;
        *(half4*)(dst + o + 1024) = hb;
    } else {                               // minmax (1 block)
        __shared__ float smn[256], smx[256];
        float mn = 3.0e38f, mx = -3.0e38f;
        for (int i = tid; i < 4096; i += 256) { mn = fminf(mn, pmin[i]); mx = fmaxf(mx, pmax[i]); }
        smn[tid] = mn; smx[tid] = mx;
        __syncthreads();
        for (int s = 128; s > 0; s >>= 1) {
            if (tid < s) { smn[tid] = fminf(smn[tid], smn[tid + s]); smx[tid] = fmaxf(smx[tid], smx[tid + s]); }
            __syncthreads();
        }
        if (tid == 0) { scal[0] = smn[0]; scal[1] = 1.0f / (smx[0] - smn[0]); }
    }
}

// attn: gemm2p<2,16>, 256x128 tile per (bh, m-block). grid 256 = 1 blk/CU.
__global__ __launch_bounds__(512, 2) void k_gemm_attn2(const _Float16* __restrict__ awr,
                                                       const _Float16* __restrict__ Bv,
                                                       _Float16* __restrict__ Aattn,
                                                       const float* __restrict__ scal,
                                                       const float* __restrict__ colsum) {
    const int bid = blockIdx.x;
    const int wg  = (bid & 7) * 32 + (bid >> 3);   // bijective (256 = 8*32)
    const int bh  = wg >> 2, mb = wg & 3;
    const int m0  = mb * 256;
    f32x4 acc[8][2];
    gemm2p<2, 16>(awr + ((size_t)bh << 20) + (size_t)m0 * 1024,
                  Bv + (size_t)bh * 131072, 1024, 1024, acc);
    const int lane = threadIdx.x & 63;
    const int w    = threadIdx.x >> 6;
    const int wr   = w >> 2, wc = w & 3;
    const int quad = lane >> 4, l16 = lane & 15;
    const float sc = scal[1];
    const float c0 = sc * scal[0];
    const int b = bh >> 4, h = bh & 15;
    #pragma unroll
    for (int m = 0; m < 8; m++)
        #pragma unroll
        for (int j = 0; j < 2; j++)
            #pragma unroll
            for (int r = 0; r < 4; r++) {
                int mm = m0 + wr * 128 + m * 16 + quad * 4 + r;  // q position
                int n  = wc * 32 + j * 16 + l16;                 // 0..127
                float v = sc * acc[m][j][r] - c0 * colsum[bh * 128 + n];
                int e = (n < 64) ? (h * 64 + n) : (1024 + h * 64 + n - 64);
                Aattn[(size_t)(mm * 4 + b) * 2048 + e] = (_Float16)v;
            }
}

// out-projection: gemm2p<2,32>, 256x128 tile, K=2048. grid 256 = 16my x 8nx x 2z.
__global__ __launch_bounds__(512, 2) void k_gemm_out2b(const _Float16* __restrict__ A,
                                                       const _Float16* __restrict__ Bre,
                                                       const _Float16* __restrict__ Bim,
                                                       float* __restrict__ outp,
                                                       const float* __restrict__ ob_re,
                                                       const float* __restrict__ ob_im) {
    const int bid = blockIdx.x;
    const int wg  = (bid & 7) * 32 + (bid >> 3);   // bijective (256 = 8*32)
    const int my  = wg >> 4;
    const int nxz = wg & 15;
    const int z   = nxz >> 3, nx = nxz & 7;
    const _Float16* B = z ? Bim : Bre;
    const float* bias = z ? ob_im : ob_re;
    float* out = outp + (size_t)z * 4194304;
    const int m0 = my * 256, n0 = nx * 128;
    f32x4 acc[8][2];
    gemm2p<2, 32>(A + (size_t)m0 * 2048, B + (size_t)n0 * 2048, 2048, 2048, acc);
    const int lane = threadIdx.x & 63;
    const int w    = threadIdx.x >> 6;
    const int wr   = w >> 2, wc = w & 3;
    const int quad = lane >> 4, l16 = lane & 15;
    #pragma unroll
    for (int m = 0; m < 8; m++)
        #pragma unroll
        for (int j = 0; j < 2; j++)
            #pragma unroll
            for (int r = 0; r < 4; r++) {
                int mm = m0 + wr * 128 + m * 16 + quad * 4 + r;
                int nn = n0 + wc * 32 + j * 16 + l16;
                out[((size_t)mm << 10) + nn] = acc[m][j][r] + bias[nn];
            }
}

__global__ __launch_bounds__(256) void k_awavg(const _Float16* __restrict__ awr,
                                               const float* __restrict__ scal,
                                               float* __restrict__ out) {
    int i = blockIdx.x * 256 + threadIdx.x;
    int k = (i & 127) * 8, q = (i >> 7) & 1023, b = i >> 17;
    float s[8] = {0, 0, 0, 0, 0, 0, 0, 0};
    size_t base = ((size_t)b << 24) + ((size_t)q << 10) + k;
    #pragma unroll
    for (int h = 0; h < 16; h++) {
        half8 v = *(const half8*)(awr + base + ((size_t)h << 20));
        #pragma unroll
        for (int e = 0; e < 8; e++) s[e] += (float)v[e];
    }
    const float mn = scal[0], sc = scal[1];
    float* dst = out + ((size_t)b << 20) + ((size_t)q << 10) + k;
    f32x4 o0, o1;
    #pragma unroll
    for (int e = 0; e < 4; e++) o0[e] = (s[e] * 0.0625f - mn) * sc;
    #pragma unroll
    for (int e = 0; e < 4; e++) o1[e] = (s[4 + e] * 0.0625f - mn) * sc;
    *(f32x4*)dst = o0;
    *(f32x4*)(dst + 4) = o1;
}

extern "C" void kernel_launch(void* const* d_in, const int* in_sizes, int n_in,
                              void* d_out, int out_size, void* d_ws, size_t ws_size,
                              hipStream_t stream) {
    const float* x_re  = (const float*)d_in[0];
    const float* x_im  = (const float*)d_in[1];
    const float* w_re  = (const float*)d_in[2];
    const float* w_im  = (const float*)d_in[3];
    const float* b_re  = (const float*)d_in[4];
    const float* b_im  = (const float*)d_in[5];
    const float* ow_re = (const float*)d_in[6];
    const float* ow_im = (const float*)d_in[7];
    const float* ob_re = (const float*)d_in[8];
    const float* ob_im = (const float*)d_in[9];

    char* ws = (char*)d_ws;
    _Float16* AWR   = (_Float16*)(ws + OFF_AWR);
    _Float16* AQ    = (_Float16*)(ws + OFF_AQ);
    _Float16* BK    = (_Float16*)(ws + OFF_BK);
    _Float16* BV    = (_Float16*)(ws + OFF_BV);
    _Float16* AATTN = (_Float16*)(ws + OFF_AATTN);
    _Float16* BORE  = (_Float16*)(ws + OFF_BORE);
    _Float16* BOIM  = (_Float16*)(ws + OFF_BOIM);
    float*    CSUM  = (float*)(ws + OFF_COLSUM);
    float*    PMIN  = (float*)(ws + OFF_PMIN);
    float*    PMAX  = (float*)(ws + OFF_PMAX);
    float*    SCAL  = (float*)(ws + OFF_SCAL);
    _Float16* AK    = (_Float16*)(ws + OFF_AK0);
    _Float16* BW    = (_Float16*)(ws + OFF_BW0);
    _Float16* PT    = (_Float16*)(ws + OFF_PT0);

    // 1. Karatsuba operand packing (one dispatch)
    k_pack3_all<<<7168, 256, 0, stream>>>(AK, BW, x_re, x_im, w_re, w_im);
    // 2. in-projection: 3 Karatsuba GEMMs (K=1024), 768 blocks x 512 thr
    k_gemm_proj<<<768, 512, 0, stream>>>(AK, BW, PT);
    // 3. qkv repack
    dim3 gp(16, 64);
    k_pack_qk<<<gp, 256, 0, stream>>>(PT, PT + PT_STRIDE / 2, PT + PT_STRIDE,
                                      b_re, b_im, AQ, BK, BV);
    // 4. QK^T (re+im fused into one real GEMM) + min/max partials
    dim3 g2(8, 8, 64);
    k_gemm_qk<<<g2, 256, 0, stream>>>(AQ, BK, AWR, PMIN, PMAX);
    // 5. fused small work: minmax + colsum + out-proj operand packing
    k_small_fused<<<4097, 256, 0, stream>>>(PMIN, PMAX, SCAL, BV, CSUM,
                                            BORE, BOIM, ow_re, ow_im);
    // 6. attention x V with affine correction (256 blocks, pipelined core)
    k_gemm_attn2<<<256, 512, 0, stream>>>(AWR, BV, AATTN, SCAL, CSUM);
    // 7. out-projection (256 blocks, K=2048, pipelined core)
    k_gemm_out2b<<<256, 512, 0, stream>>>(AATTN, BORE, BOIM, (float*)d_out,
                                          ob_re, ob_im);
    // 8. head-averaged attention map
    k_awavg<<<2048, 256, 0, stream>>>(AWR, SCAL, (float*)d_out + 8388608);
}